// Round 10
// baseline (2530.229 us; speedup 1.0000x reference)
//
#include <hip/hip_runtime.h>

// SpatialAttentionLSTMDecoder on MI355X (gfx950). B=128,T=32,V=10000,F=H=768,R=49.
// R10: 4 launches/step. LSTM fused into g2m via split-K last-block finisher
// (interleaved gate layout j'=4*hh+gate; per-tile atomic flag; threadfence
// release/acquire; h state ping-pongs through H_all so no same-kernel RAW).
// g1a (h@Wh splitK3) -> scores -> ctx -> g2m_lstm. fc = proven R7 256-thr EPI2.

typedef _Float16 f16x8 __attribute__((ext_vector_type(8)));
typedef _Float16 f16x4 __attribute__((ext_vector_type(4)));
typedef float f32x4 __attribute__((ext_vector_type(4)));

#define NB 128
#define NT 32
#define NV 10000
#define NH 768
#define NR 49
#define OUT_ELEMS 40960000  // B*T*V

__device__ __forceinline__ float fast_tanh(float x) {
  x = fminf(9.f, fmaxf(-9.f, x));
  float e = __expf(2.f * x);
  return (e - 1.f) / (e + 1.f);
}
__device__ __forceinline__ float sigm(float x) { return 1.f / (1.f + __expf(-x)); }

__device__ __forceinline__ void gld16(const void* g, void* l) {
  __builtin_amdgcn_global_load_lds((const __attribute__((address_space(1))) void*)g,
                                   (__attribute__((address_space(3))) void*)l, 16, 0, 0);
}

// ---------------- 64x64 split-K GEMM (g1a), EPI: f32 partial at z*128*N ----------------
template <int KSTEPS, int KSPLIT>
__global__ __launch_bounds__(256) void gemm64(
    const _Float16* __restrict__ A, const _Float16* __restrict__ Bt,
    float* __restrict__ C, int N) {
  constexpr int BK = 64;
  __shared__ __attribute__((aligned(16))) _Float16 sAB[128 * BK];
  _Float16* sA = sAB;
  _Float16* sB = sAB + 64 * BK;
  const int tid = threadIdx.x;
  const int m0 = blockIdx.x * 64, n0 = blockIdx.y * 64;
  const int z = blockIdx.z;
  A += (size_t)z * KSPLIT;
  Bt += (size_t)z * KSPLIT;
  C += (size_t)z * 128 * N;

  const int wid = tid >> 6, lane = tid & 63;
  const int wr = wid >> 1, wc = wid & 1;
  const int lr = lane & 15, lk = (lane >> 4) * 8;

  f32x4 acc[2][2] = {};

  for (int kt = 0; kt < KSTEPS; ++kt) {
    const int kbase = kt * BK;
#pragma unroll
    for (int i = 0; i < 2; i++) {
      int idx = tid + i * 256;
      int row = idx >> 3, seg = idx & 7;
      gld16(A + (size_t)(m0 + row) * NH + kbase + seg * 8, sA + idx * 8);
      gld16(Bt + (size_t)(n0 + row) * NH + kbase + seg * 8, sB + idx * 8);
    }
    __syncthreads();
#pragma unroll
    for (int kk = 0; kk < 2; ++kk) {
      f16x8 af[2], bf[2];
#pragma unroll
      for (int m = 0; m < 2; m++)
        af[m] = *(const f16x8*)&sA[(wr * 32 + m * 16 + lr) * BK + kk * 32 + lk];
#pragma unroll
      for (int n = 0; n < 2; n++)
        bf[n] = *(const f16x8*)&sB[(wc * 32 + n * 16 + lr) * BK + kk * 32 + lk];
#pragma unroll
      for (int m = 0; m < 2; m++)
#pragma unroll
        for (int n = 0; n < 2; n++)
          acc[m][n] = __builtin_amdgcn_mfma_f32_16x16x32_f16(af[m], bf[n], acc[m][n], 0, 0, 0);
    }
    __syncthreads();
  }

  const int rowb = (lane >> 4) * 4;
#pragma unroll
  for (int m = 0; m < 2; m++) {
    int gm = m0 + wr * 32 + m * 16 + rowb;
#pragma unroll
    for (int n = 0; n < 2; n++) {
      int gn = n0 + wc * 32 + n * 16 + lr;
#pragma unroll
      for (int j = 0; j < 4; j++) C[(size_t)(gm + j) * N + gn] = acc[m][n][j];
    }
  }
}

// ---------------- g2m + fused LSTM finisher ----------------
// z<2: ctx@Wc_int splitK2 halves; z>=2: hprev@Whh_int splitK2 halves.
// Last of 4 blocks per (bx,by) tile sums partials + Gemb_int + bias_int -> LSTM.
__global__ __launch_bounds__(256) void g2m_lstm(
    const _Float16* __restrict__ ctx16, const _Float16* __restrict__ Wc_int,
    const _Float16* __restrict__ hprev, const _Float16* __restrict__ Whh_int,
    float* __restrict__ gbuf, const _Float16* __restrict__ ge_t,
    const float* __restrict__ bias_int, float* __restrict__ cst,
    float* __restrict__ hst, _Float16* __restrict__ hnext,
    unsigned* __restrict__ flags) {
  constexpr int BK = 64;
  __shared__ __attribute__((aligned(16))) _Float16 sAB[128 * BK];
  _Float16* sA = sAB;
  _Float16* sB = sAB + 64 * BK;
  const int tid = threadIdx.x;
  const int m0 = blockIdx.x * 64, n0 = blockIdx.y * 64;
  const int z = blockIdx.z;
  const _Float16* A = (z >> 1) ? hprev : ctx16;
  const _Float16* Bt = (z >> 1) ? Whh_int : Wc_int;
  A += (size_t)(z & 1) * 384;
  Bt += (size_t)(z & 1) * 384;
  float* C = gbuf + (size_t)z * NB * 3072;

  const int wid = tid >> 6, lane = tid & 63;
  const int wr = wid >> 1, wc = wid & 1;
  const int lr = lane & 15, lk = (lane >> 4) * 8;

  f32x4 acc[2][2] = {};

  for (int kt = 0; kt < 6; ++kt) {
    const int kbase = kt * BK;
#pragma unroll
    for (int i = 0; i < 2; i++) {
      int idx = tid + i * 256;
      int row = idx >> 3, seg = idx & 7;
      gld16(A + (size_t)(m0 + row) * NH + kbase + seg * 8, sA + idx * 8);
      gld16(Bt + (size_t)(n0 + row) * NH + kbase + seg * 8, sB + idx * 8);
    }
    __syncthreads();
#pragma unroll
    for (int kk = 0; kk < 2; ++kk) {
      f16x8 af[2], bf[2];
#pragma unroll
      for (int m = 0; m < 2; m++)
        af[m] = *(const f16x8*)&sA[(wr * 32 + m * 16 + lr) * BK + kk * 32 + lk];
#pragma unroll
      for (int n = 0; n < 2; n++)
        bf[n] = *(const f16x8*)&sB[(wc * 32 + n * 16 + lr) * BK + kk * 32 + lk];
#pragma unroll
      for (int m = 0; m < 2; m++)
#pragma unroll
        for (int n = 0; n < 2; n++)
          acc[m][n] = __builtin_amdgcn_mfma_f32_16x16x32_f16(af[m], bf[n], acc[m][n], 0, 0, 0);
    }
    __syncthreads();
  }

  const int rowb = (lane >> 4) * 4;
#pragma unroll
  for (int m = 0; m < 2; m++) {
    int gm = m0 + wr * 32 + m * 16 + rowb;
#pragma unroll
    for (int n = 0; n < 2; n++) {
      int gn = n0 + wc * 32 + n * 16 + lr;
#pragma unroll
      for (int j = 0; j < 4; j++) C[(size_t)(gm + j) * 3072 + gn] = acc[m][n][j];
    }
  }

  // ---- split-K finisher: last block of the 4 sharing (bx,by) does the LSTM ----
  __threadfence();  // release: partials visible device-wide before flag bump
  __syncthreads();
  __shared__ unsigned s_old;
  if (tid == 0) s_old = atomicAdd(&flags[blockIdx.x * 48 + blockIdx.y], 1u);
  __syncthreads();
  if (s_old != 3u) return;
  __threadfence();  // acquire: invalidate L1 so partial reads are fresh

  const int b_l = tid & 63, q = tid >> 6;
  const int b_g = m0 + b_l;
  const float* g0 = gbuf + (size_t)b_g * 3072;
  const float* g1 = g0 + (size_t)NB * 3072;
  const float* g2 = g1 + (size_t)NB * 3072;
  const float* g3 = g2 + (size_t)NB * 3072;
#pragma unroll
  for (int i = 0; i < 4; i++) {
    int hh_l = q * 4 + i;             // 0..15
    int hh_g = (n0 >> 2) + hh_l;      // global hh
    int colj = n0 + 4 * hh_l;         // interleaved gate quad
    f32x4 s0 = *(const f32x4*)&g0[colj];
    f32x4 s1 = *(const f32x4*)&g1[colj];
    f32x4 s2 = *(const f32x4*)&g2[colj];
    f32x4 s3 = *(const f32x4*)&g3[colj];
    f16x4 ge = *(const f16x4*)&ge_t[(size_t)b_g * 3072 + colj];
    f32x4 bi = *(const f32x4*)&bias_int[colj];
    float gi = s0[0] + s1[0] + s2[0] + s3[0] + (float)ge[0] + bi[0];
    float gf = s0[1] + s1[1] + s2[1] + s3[1] + (float)ge[1] + bi[1];
    float gg = s0[2] + s1[2] + s2[2] + s3[2] + (float)ge[2] + bi[2];
    float go = s0[3] + s1[3] + s2[3] + s3[3] + (float)ge[3] + bi[3];
    float cn = sigm(gf) * cst[b_g * NH + hh_g] + sigm(gi) * fast_tanh(gg);
    float hn = sigm(go) * fast_tanh(cn);
    cst[b_g * NH + hh_g] = cn;
    hst[b_g * NH + hh_g] = hn;
    hnext[(size_t)b_g * NH + hh_g] = (_Float16)hn;
  }
}

// ---------------- phase-A merged 128x128 GEMM: fp16 proj (294 blk) + Gemb (768 blk) ----------------
__global__ __launch_bounds__(256) void gemm_phA(
    const _Float16* __restrict__ feat16, const _Float16* __restrict__ Wf16,
    const float* __restrict__ attn_b, _Float16* __restrict__ fp16,
    const _Float16* __restrict__ emb16, const _Float16* __restrict__ We16,
    _Float16* __restrict__ Gemb16) {
  constexpr int BK = 64;
  __shared__ __attribute__((aligned(16))) _Float16 sAB[256 * BK];
  _Float16* sA = sAB;
  _Float16* sB = sAB + 128 * BK;
  const int blk = blockIdx.x, tid = threadIdx.x;
  const bool isFP = blk < 294;
  const int bx = isFP ? (blk % 49) : ((blk - 294) % 32);
  const int by = isFP ? (blk / 49) : ((blk - 294) / 32);
  const _Float16* A = isFP ? feat16 : emb16;
  const _Float16* Bt = isFP ? Wf16 : We16;
  const int m0 = bx * 128, n0 = by * 128;

  const int wid = tid >> 6, lane = tid & 63;
  const int wr = wid >> 1, wc = wid & 1;
  const int lr = lane & 15, lk = (lane >> 4) * 8;

  f32x4 acc[4][4] = {};

  for (int kt = 0; kt < 12; ++kt) {
    const int kbase = kt * BK;
#pragma unroll
    for (int i = 0; i < 4; i++) {
      int idx = tid + i * 256;
      int row = idx >> 3, seg = idx & 7;
      gld16(A + (size_t)(m0 + row) * NH + kbase + seg * 8, sA + idx * 8);
      gld16(Bt + (size_t)(n0 + row) * NH + kbase + seg * 8, sB + idx * 8);
    }
    __syncthreads();
#pragma unroll
    for (int kk = 0; kk < 2; ++kk) {
      f16x8 af[4], bf[4];
#pragma unroll
      for (int m = 0; m < 4; m++)
        af[m] = *(const f16x8*)&sA[(wr * 64 + m * 16 + lr) * BK + kk * 32 + lk];
#pragma unroll
      for (int n = 0; n < 4; n++)
        bf[n] = *(const f16x8*)&sB[(wc * 64 + n * 16 + lr) * BK + kk * 32 + lk];
#pragma unroll
      for (int m = 0; m < 4; m++)
#pragma unroll
        for (int n = 0; n < 4; n++)
          acc[m][n] = __builtin_amdgcn_mfma_f32_16x16x32_f16(af[m], bf[n], acc[m][n], 0, 0, 0);
    }
    __syncthreads();
  }

  const int rowb = (lane >> 4) * 4;
#pragma unroll
  for (int m = 0; m < 4; m++) {
    int gm = m0 + wr * 64 + m * 16 + rowb;
#pragma unroll
    for (int n = 0; n < 4; n++) {
      int gn = n0 + wc * 64 + n * 16 + lr;
#pragma unroll
      for (int j = 0; j < 4; j++) {
        if (isFP)
          fp16[(size_t)(gm + j) * NH + gn] = (_Float16)(acc[m][n][j] + attn_b[gn]);
        else
          Gemb16[(size_t)(gm + j) * 3072 + gn] = (_Float16)acc[m][n][j];
      }
    }
  }
}

// ---------------- fc GEMM: R7-proven 256-thr, LDS-staged f32x4 epilogue ----------------
__global__ __launch_bounds__(256) void gemm_fc(
    const _Float16* __restrict__ A, const _Float16* __restrict__ Bt,
    float* __restrict__ out, const float* __restrict__ bias, int N) {
  constexpr int BK = 64;
  __shared__ __attribute__((aligned(16))) _Float16 sAB[256 * BK];
  _Float16* sA = sAB;
  _Float16* sB = sAB + 128 * BK;
  const int tid = threadIdx.x;
  const int m0 = blockIdx.x * 128, n0 = blockIdx.y * 128;
  const int wid = tid >> 6, lane = tid & 63;
  const int wr = wid >> 1, wc = wid & 1;
  const int lr = lane & 15, lk = (lane >> 4) * 8;

  f32x4 acc[4][4] = {};

  for (int kt = 0; kt < 12; ++kt) {
    const int kbase = kt * BK;
#pragma unroll
    for (int i = 0; i < 4; i++) {
      int idx = tid + i * 256;
      int row = idx >> 3, seg = idx & 7;
      gld16(A + (size_t)(m0 + row) * NH + kbase + seg * 8, sA + idx * 8);
      int gr = n0 + row;
      if (gr >= N) gr = N - 1;
      gld16(Bt + (size_t)gr * NH + kbase + seg * 8, sB + idx * 8);
    }
    __syncthreads();
#pragma unroll
    for (int kk = 0; kk < 2; ++kk) {
      f16x8 af[4], bf[4];
#pragma unroll
      for (int m = 0; m < 4; m++)
        af[m] = *(const f16x8*)&sA[(wr * 64 + m * 16 + lr) * BK + kk * 32 + lk];
#pragma unroll
      for (int n = 0; n < 4; n++)
        bf[n] = *(const f16x8*)&sB[(wc * 64 + n * 16 + lr) * BK + kk * 32 + lk];
#pragma unroll
      for (int m = 0; m < 4; m++)
#pragma unroll
        for (int n = 0; n < 4; n++)
          acc[m][n] = __builtin_amdgcn_mfma_f32_16x16x32_f16(af[m], bf[n], acc[m][n], 0, 0, 0);
    }
    __syncthreads();
  }

  const int rowb = (lane >> 4) * 4;
  float* sC = (float*)sAB;  // 64x128 f32 = 32 KB
#pragma unroll
  for (int h = 0; h < 2; h++) {
    if (wr == h) {
#pragma unroll
      for (int m = 0; m < 4; m++)
#pragma unroll
        for (int n = 0; n < 4; n++)
#pragma unroll
          for (int j = 0; j < 4; j++)
            sC[(m * 16 + rowb + j) * 128 + wc * 64 + n * 16 + lr] = acc[m][n][j];
    }
    __syncthreads();
#pragma unroll
    for (int i = 0; i < 8; i++) {
      int lrow = (tid >> 5) + i * 8;
      int col = (tid & 31) * 4;
      int gn = n0 + col;
      if (gn < N) {
        int r = m0 + h * 64 + lrow;
        int tt = r >> 7, b = r & 127;
        f32x4 val = *(f32x4*)&sC[lrow * 128 + col];
        f32x4 bb = *(const f32x4*)&bias[gn];
        val += bb;
        *(f32x4*)&out[((size_t)(b * NT + tt)) * NV + gn] = val;
      }
    }
    __syncthreads();
  }
}

// ---------------- loop elementwise kernels ----------------
__global__ __launch_bounds__(256) void k_scores(
    const _Float16* __restrict__ fp, const float* __restrict__ g1a,
    const float* __restrict__ v, float* __restrict__ sc) {
  int wid = threadIdx.x >> 6, lane = threadIdx.x & 63;
  int p = blockIdx.x * 4 + wid;  // 6272 = 1568 blocks * 4 waves
  int b = p / NR;
  const _Float16* fpr = fp + (size_t)p * NH;
  const float* hw0 = g1a + (size_t)b * NH;
  const float* hw1 = g1a + (size_t)NB * NH + (size_t)b * NH;
  const float* hw2 = g1a + (size_t)2 * NB * NH + (size_t)b * NH;
  float s = 0.f;
#pragma unroll
  for (int it = 0; it < 3; it++) {
    int h = it * 256 + lane * 4;
    f16x4 fv = *(const f16x4*)(fpr + h);
    f32x4 a0 = *(const f32x4*)(hw0 + h);
    f32x4 a1 = *(const f32x4*)(hw1 + h);
    f32x4 a2 = *(const f32x4*)(hw2 + h);
    f32x4 vv = *(const f32x4*)(v + h);
#pragma unroll
    for (int j = 0; j < 4; j++) s += fast_tanh((float)fv[j] + a0[j] + a1[j] + a2[j]) * vv[j];
  }
#pragma unroll
  for (int off = 32; off; off >>= 1) s += __shfl_down(s, off);
  if (lane == 0) sc[p] = s;
}

__global__ __launch_bounds__(256) void k_ctx(const float* __restrict__ sc,
                                             const _Float16* __restrict__ feat16,
                                             _Float16* __restrict__ ctx16) {
  __shared__ float al[64];
  int b = blockIdx.x, tid = threadIdx.x;
  if (tid < 64) {
    float s = (tid < NR) ? sc[b * NR + tid] : -1e30f;
    float m = s;
#pragma unroll
    for (int off = 32; off; off >>= 1) m = fmaxf(m, __shfl_xor(m, off));
    float e = (tid < NR) ? __expf(s - m) : 0.f;
    float su = e;
#pragma unroll
    for (int off = 32; off; off >>= 1) su += __shfl_xor(su, off);
    al[tid] = e / su;
  }
  __syncthreads();
  int f = blockIdx.y * 256 + tid;
  const _Float16* fb = feat16 + (size_t)b * NR * NH + f;
  float acc = 0.f;
#pragma unroll
  for (int r = 0; r < NR; r++) acc += al[r] * (float)fb[(size_t)r * NH];
  ctx16[(size_t)b * NH + f] = (_Float16)acc;
}

// ---------------- phase-A prep: one kernel, block-range dispatch ----------------
// S0 feat16(18816) | S1 Wf16(2304) | S2 Wh16(2304) | S3 Whh_int(9216) |
// S4 We_int(9216) | S5 Wc_int(9216) | S6 emb16(12288) | S7 init(384) |
// S8 flags(12) | S9 bias_int(12)
__global__ void k_prep(const float* __restrict__ features, const float* __restrict__ attn_W,
                       const float* __restrict__ W_ih, const float* __restrict__ W_hh,
                       const int* __restrict__ captions, const float* __restrict__ emb_W,
                       const float* __restrict__ b_ih, const float* __restrict__ b_hh,
                       _Float16* __restrict__ feat16, _Float16* __restrict__ Wf16,
                       _Float16* __restrict__ Wh16, _Float16* __restrict__ Whh_int,
                       _Float16* __restrict__ We_int, _Float16* __restrict__ Wc_int,
                       _Float16* __restrict__ emb16, float* __restrict__ h,
                       float* __restrict__ c, _Float16* __restrict__ h0_16,
                       unsigned* __restrict__ flags, float* __restrict__ bias_int) {
  const int blk = blockIdx.x, tid = threadIdx.x;
  if (blk < 18816) {
    int i = blk * 256 + tid;
    feat16[i] = (_Float16)features[i];
  } else if (blk < 21120) {
    int q = (blk - 18816) * 256 + tid;
    int j = q / NH, k = q - j * NH;
    Wf16[q] = (_Float16)attn_W[(size_t)j * 1536 + k];
  } else if (blk < 23424) {
    int q = (blk - 21120) * 256 + tid;
    int j = q / NH, k = q - j * NH;
    Wh16[q] = (_Float16)attn_W[(size_t)j * 1536 + 768 + k];
  } else if (blk < 32640) {
    int q = (blk - 23424) * 256 + tid;
    int jp = q / NH, k = q - jp * NH;
    int src = (jp & 3) * NH + (jp >> 2);
    Whh_int[q] = (_Float16)W_hh[(size_t)src * NH + k];
  } else if (blk < 41856) {
    int q = (blk - 32640) * 256 + tid;
    int jp = q / NH, k = q - jp * NH;
    int src = (jp & 3) * NH + (jp >> 2);
    We_int[q] = (_Float16)W_ih[(size_t)src * 1536 + k];
  } else if (blk < 51072) {
    int q = (blk - 41856) * 256 + tid;
    int jp = q / NH, k = q - jp * NH;
    int src = (jp & 3) * NH + (jp >> 2);
    Wc_int[q] = (_Float16)W_ih[(size_t)src * 1536 + 768 + k];
  } else if (blk < 63360) {
    int q = (blk - 51072) * 256 + tid;
    int row = q / NH, k = q - row * NH;  // row = t*128+b
    int t = row >> 7, b = row & 127;
    int tok = captions[b * NT + t];
    emb16[q] = (_Float16)emb_W[(size_t)tok * NH + k];
  } else if (blk < 63744) {
    int q = blk - 63360;  // 384: b = q/3, f-chunk = q%3
    int b = q / 3;
    int f = (q - b * 3) * 256 + tid;
    float s = 0.f;
#pragma unroll 7
    for (int r = 0; r < NR; r++) s += features[((size_t)(b * NR + r)) * NH + f];
    float h0 = tanhf(s * (1.f / 49.f));
    h[b * NH + f] = h0;
    c[b * NH + f] = 0.f;
    h0_16[(size_t)b * NH + f] = (_Float16)h0;
  } else if (blk < 63756) {
    flags[(blk - 63744) * 256 + tid] = 0u;  // 3072 flags (32 steps x 96 tiles)
  } else {
    int q = (blk - 63756) * 256 + tid;  // 3072 bias_int
    int src = (q & 3) * NH + (q >> 2);
    bias_int[q] = b_ih[src] + b_hh[src];
  }
}

__global__ void k_f32_to_f16(const float* __restrict__ src, _Float16* __restrict__ dst, int n) {
  int i = blockIdx.x * 256 + threadIdx.x;
  if (i < n) dst[i] = (_Float16)src[i];
}

__global__ void k_tail(const float* __restrict__ h, const float* __restrict__ c,
                       float* __restrict__ out) {
  int i = blockIdx.x * 256 + threadIdx.x;  // 98304
  out[OUT_ELEMS + i] = h[i];
  out[OUT_ELEMS + NB * NH + i] = c[i];
}

// ---------------- host ----------------
extern "C" void kernel_launch(void* const* d_in, const int* in_sizes, int n_in,
                              void* d_out, int out_size, void* d_ws, size_t ws_size,
                              hipStream_t stream) {
  const float* features = (const float*)d_in[0];
  const int* captions = (const int*)d_in[1];
  const float* emb_W = (const float*)d_in[2];
  const float* attn_W = (const float*)d_in[3];
  const float* attn_b = (const float*)d_in[4];
  const float* attnv_W = (const float*)d_in[5];
  // d_in[6] attnv_b: constant shift, cancels in softmax
  const float* W_ih = (const float*)d_in[7];
  const float* W_hh = (const float*)d_in[8];
  const float* b_ih = (const float*)d_in[9];
  const float* b_hh = (const float*)d_in[10];
  const float* fc_W = (const float*)d_in[11];
  const float* fc_b = (const float*)d_in[12];
  float* out = (float*)d_out;

  char* p = (char*)d_ws;
  _Float16* Gemb16 = (_Float16*)p;  p += 25165824;  // (4096,3072) interleaved; aliased by fcW16
  _Float16* fcW16 = Gemb16;                         // (10000,768), reuse after loop
  _Float16* emb16 = (_Float16*)p;   p += 6291456;   // (4096,768): row t*128+b
  _Float16* feat16 = (_Float16*)p;  p += 9633792;   // (6272,768)
  _Float16* fp16 = (_Float16*)p;    p += 9633792;   // feat_proj + attn_b (6272,768)
  _Float16* Wf16 = (_Float16*)p;    p += 1179648;   // (768,768)
  _Float16* Wh16 = (_Float16*)p;    p += 1179648;   // (768,768)
  _Float16* Whh_int = (_Float16*)p; p += 4718592;   // (3072,768) interleaved
  _Float16* We_int = (_Float16*)p;  p += 4718592;   // (3072,768) interleaved
  _Float16* Wc_int = (_Float16*)p;  p += 4718592;   // (3072,768) interleaved
  _Float16* H_all = (_Float16*)p;   p += 6291456;   // (4096,768): row t*128+b = h(t+1)
  _Float16* h0_16 = (_Float16*)p;   p += 196608;    // (128,768)
  float* g1a = (float*)p;           p += 1179648;   // 3 x (128,768) partials
  float* gbuf = (float*)p;          p += 6291456;   // 4 x (128,3072) partials
  float* scores = (float*)p;        p += 25088;     // (6272,)
  _Float16* ctx16 = (_Float16*)p;   p += 196608;    // (128,768)
  float* hbuf = (float*)p;          p += 393216;
  float* cbuf = (float*)p;          p += 393216;
  float* bias_int = (float*)p;      p += 12288;     // (3072,)
  unsigned* flags = (unsigned*)p;   p += 12288;     // 32 x 96 tile flags

  // ---- phase A: 2 launches ----
  k_prep<<<dim3(63768), 256, 0, stream>>>(features, attn_W, W_ih, W_hh, captions, emb_W,
                                          b_ih, b_hh, feat16, Wf16, Wh16, Whh_int,
                                          We_int, Wc_int, emb16, hbuf, cbuf, h0_16,
                                          flags, bias_int);
  // fp16 = feat@Wf.T + attn_b (294 blk) ; Gemb = emb@We_int.T (768 blk, interleaved)
  gemm_phA<<<dim3(1062), 256, 0, stream>>>(feat16, Wf16, attn_b, fp16, emb16, We_int, Gemb16);

  // ---- sequential scan: 4 launches/step ----
  for (int t = 0; t < NT; t++) {
    const _Float16* hin = (t == 0) ? h0_16 : H_all + (size_t)(t - 1) * NB * NH;
    // g1a = h @ Wh.T  (128x768, K=768 split-K3 -> 4 ksteps, 72 blocks)
    gemm64<4, 256><<<dim3(2, 12, 3), 256, 0, stream>>>(hin, Wh16, g1a, NH);
    k_scores<<<dim3(1568), 256, 0, stream>>>(fp16, g1a, attnv_W, scores);
    k_ctx<<<dim3(128, 3), 256, 0, stream>>>(scores, feat16, ctx16);
    // gbuf = {ctx@Wc_int | h@Whh_int} partials + fused LSTM finisher
    g2m_lstm<<<dim3(2, 48, 4), 256, 0, stream>>>(
        ctx16, Wc_int, hin, Whh_int, gbuf, Gemb16 + (size_t)t * NB * 3072, bias_int,
        cbuf, hbuf, H_all + (size_t)t * NB * NH, flags + (size_t)t * 96);
  }

  // ---- fc (fcW16 aliases Gemb16, safe after loop in stream order) ----
  k_f32_to_f16<<<dim3(30000), 256, 0, stream>>>(fc_W, fcW16, 7680000);
  gemm_fc<<<dim3(32, 79), 256, 0, stream>>>(H_all, fcW16, out, fc_b, NV);
  k_tail<<<dim3(384), 256, 0, stream>>>(hbuf, cbuf, out);
}

// Round 11
// 1036.169 us; speedup vs baseline: 2.4419x; 2.4419x over previous
//
#include <hip/hip_runtime.h>

// SpatialAttentionLSTMDecoder on MI355X (gfx950). B=128,T=32,V=10000,F=H=768,R=49.
// R11 = R9 (best, 1022.7us) + vectorized prep/convert (f32x4->f16x4) + k_tail
// folded into gemm_fc. Loop structure frozen: 5 launches/step
// (lstm2 -> g1a splitK3 -> scores -> ctx -> g2m). NO inter-block sync anywhere
// (R5 grid-barrier: 118us/sync; R10 splitK-finisher: +47us/step — both XCD-
// coherence-bound). fc = proven 256-thr EPI2 (R8 showed it's not occupancy-bound).

typedef _Float16 f16x8 __attribute__((ext_vector_type(8)));
typedef _Float16 f16x4 __attribute__((ext_vector_type(4)));
typedef float f32x4 __attribute__((ext_vector_type(4)));

#define NB 128
#define NT 32
#define NV 10000
#define NH 768
#define NR 49
#define OUT_ELEMS 40960000  // B*T*V

__device__ __forceinline__ float fast_tanh(float x) {
  x = fminf(9.f, fmaxf(-9.f, x));
  float e = __expf(2.f * x);
  return (e - 1.f) / (e + 1.f);
}
__device__ __forceinline__ float sigm(float x) { return 1.f / (1.f + __expf(-x)); }

__device__ __forceinline__ void gld16(const void* g, void* l) {
  __builtin_amdgcn_global_load_lds((const __attribute__((address_space(1))) void*)g,
                                   (__attribute__((address_space(3))) void*)l, 16, 0, 0);
}

__device__ __forceinline__ f16x4 cvt4(f32x4 v) {
  f16x4 o;
#pragma unroll
  for (int j = 0; j < 4; j++) o[j] = (_Float16)v[j];
  return o;
}

// ---------------- 64x64 split-K GEMM (loop), EPI: f32 partial at z*128*N ----------------
template <int KSTEPS, int KSPLIT>
__global__ __launch_bounds__(256) void gemm64(
    const _Float16* __restrict__ A, const _Float16* __restrict__ Bt,
    float* __restrict__ C, int N) {
  constexpr int BK = 64;
  __shared__ __attribute__((aligned(16))) _Float16 sAB[128 * BK];
  _Float16* sA = sAB;
  _Float16* sB = sAB + 64 * BK;
  const int tid = threadIdx.x;
  const int m0 = blockIdx.x * 64, n0 = blockIdx.y * 64;
  const int z = blockIdx.z;
  A += (size_t)z * KSPLIT;
  Bt += (size_t)z * KSPLIT;
  C += (size_t)z * 128 * N;

  const int wid = tid >> 6, lane = tid & 63;
  const int wr = wid >> 1, wc = wid & 1;
  const int lr = lane & 15, lk = (lane >> 4) * 8;

  f32x4 acc[2][2] = {};

  for (int kt = 0; kt < KSTEPS; ++kt) {
    const int kbase = kt * BK;
#pragma unroll
    for (int i = 0; i < 2; i++) {
      int idx = tid + i * 256;
      int row = idx >> 3, seg = idx & 7;
      gld16(A + (size_t)(m0 + row) * NH + kbase + seg * 8, sA + idx * 8);
      gld16(Bt + (size_t)(n0 + row) * NH + kbase + seg * 8, sB + idx * 8);
    }
    __syncthreads();
#pragma unroll
    for (int kk = 0; kk < 2; ++kk) {
      f16x8 af[2], bf[2];
#pragma unroll
      for (int m = 0; m < 2; m++)
        af[m] = *(const f16x8*)&sA[(wr * 32 + m * 16 + lr) * BK + kk * 32 + lk];
#pragma unroll
      for (int n = 0; n < 2; n++)
        bf[n] = *(const f16x8*)&sB[(wc * 32 + n * 16 + lr) * BK + kk * 32 + lk];
#pragma unroll
      for (int m = 0; m < 2; m++)
#pragma unroll
        for (int n = 0; n < 2; n++)
          acc[m][n] = __builtin_amdgcn_mfma_f32_16x16x32_f16(af[m], bf[n], acc[m][n], 0, 0, 0);
    }
    __syncthreads();
  }

  const int rowb = (lane >> 4) * 4;
#pragma unroll
  for (int m = 0; m < 2; m++) {
    int gm = m0 + wr * 32 + m * 16 + rowb;
#pragma unroll
    for (int n = 0; n < 2; n++) {
      int gn = n0 + wc * 32 + n * 16 + lr;
#pragma unroll
      for (int j = 0; j < 4; j++) C[(size_t)(gm + j) * N + gn] = acc[m][n][j];
    }
  }
}

// ---------------- g2m: merged ctx@Wc (z=0,1) + h@Whh (z=2,3), splitK2 each ----------------
__global__ __launch_bounds__(256) void gemm_g2m(
    const _Float16* __restrict__ ctx16, const _Float16* __restrict__ Wc,
    const _Float16* __restrict__ h16, const _Float16* __restrict__ Whh,
    float* __restrict__ C) {
  constexpr int BK = 64;
  __shared__ __attribute__((aligned(16))) _Float16 sAB[128 * BK];
  _Float16* sA = sAB;
  _Float16* sB = sAB + 64 * BK;
  const int tid = threadIdx.x;
  const int m0 = blockIdx.x * 64, n0 = blockIdx.y * 64;
  const int z = blockIdx.z;
  const _Float16* A = (z >> 1) ? h16 : ctx16;
  const _Float16* Bt = (z >> 1) ? Whh : Wc;
  A += (size_t)(z & 1) * 384;
  Bt += (size_t)(z & 1) * 384;
  C += (size_t)z * 128 * 3072;

  const int wid = tid >> 6, lane = tid & 63;
  const int wr = wid >> 1, wc = wid & 1;
  const int lr = lane & 15, lk = (lane >> 4) * 8;

  f32x4 acc[2][2] = {};

  for (int kt = 0; kt < 6; ++kt) {
    const int kbase = kt * BK;
#pragma unroll
    for (int i = 0; i < 2; i++) {
      int idx = tid + i * 256;
      int row = idx >> 3, seg = idx & 7;
      gld16(A + (size_t)(m0 + row) * NH + kbase + seg * 8, sA + idx * 8);
      gld16(Bt + (size_t)(n0 + row) * NH + kbase + seg * 8, sB + idx * 8);
    }
    __syncthreads();
#pragma unroll
    for (int kk = 0; kk < 2; ++kk) {
      f16x8 af[2], bf[2];
#pragma unroll
      for (int m = 0; m < 2; m++)
        af[m] = *(const f16x8*)&sA[(wr * 32 + m * 16 + lr) * BK + kk * 32 + lk];
#pragma unroll
      for (int n = 0; n < 2; n++)
        bf[n] = *(const f16x8*)&sB[(wc * 32 + n * 16 + lr) * BK + kk * 32 + lk];
#pragma unroll
      for (int m = 0; m < 2; m++)
#pragma unroll
        for (int n = 0; n < 2; n++)
          acc[m][n] = __builtin_amdgcn_mfma_f32_16x16x32_f16(af[m], bf[n], acc[m][n], 0, 0, 0);
    }
    __syncthreads();
  }

  const int rowb = (lane >> 4) * 4;
#pragma unroll
  for (int m = 0; m < 2; m++) {
    int gm = m0 + wr * 32 + m * 16 + rowb;
#pragma unroll
    for (int n = 0; n < 2; n++) {
      int gn = n0 + wc * 32 + n * 16 + lr;
#pragma unroll
      for (int j = 0; j < 4; j++) C[(size_t)(gm + j) * 3072 + gn] = acc[m][n][j];
    }
  }
}

// ---------------- phase-A merged 128x128 GEMM: fp16 proj (294 blk) + Gemb (768 blk) ----------------
__global__ __launch_bounds__(256) void gemm_phA(
    const _Float16* __restrict__ feat16, const _Float16* __restrict__ Wf16,
    const float* __restrict__ attn_b, _Float16* __restrict__ fp16,
    const _Float16* __restrict__ emb16, const _Float16* __restrict__ We16,
    _Float16* __restrict__ Gemb16) {
  constexpr int BK = 64;
  __shared__ __attribute__((aligned(16))) _Float16 sAB[256 * BK];
  _Float16* sA = sAB;
  _Float16* sB = sAB + 128 * BK;
  const int blk = blockIdx.x, tid = threadIdx.x;
  const bool isFP = blk < 294;
  const int bx = isFP ? (blk % 49) : ((blk - 294) % 32);
  const int by = isFP ? (blk / 49) : ((blk - 294) / 32);
  const _Float16* A = isFP ? feat16 : emb16;
  const _Float16* Bt = isFP ? Wf16 : We16;
  const int m0 = bx * 128, n0 = by * 128;

  const int wid = tid >> 6, lane = tid & 63;
  const int wr = wid >> 1, wc = wid & 1;
  const int lr = lane & 15, lk = (lane >> 4) * 8;

  f32x4 acc[4][4] = {};

  for (int kt = 0; kt < 12; ++kt) {
    const int kbase = kt * BK;
#pragma unroll
    for (int i = 0; i < 4; i++) {
      int idx = tid + i * 256;
      int row = idx >> 3, seg = idx & 7;
      gld16(A + (size_t)(m0 + row) * NH + kbase + seg * 8, sA + idx * 8);
      gld16(Bt + (size_t)(n0 + row) * NH + kbase + seg * 8, sB + idx * 8);
    }
    __syncthreads();
#pragma unroll
    for (int kk = 0; kk < 2; ++kk) {
      f16x8 af[4], bf[4];
#pragma unroll
      for (int m = 0; m < 4; m++)
        af[m] = *(const f16x8*)&sA[(wr * 64 + m * 16 + lr) * BK + kk * 32 + lk];
#pragma unroll
      for (int n = 0; n < 4; n++)
        bf[n] = *(const f16x8*)&sB[(wc * 64 + n * 16 + lr) * BK + kk * 32 + lk];
#pragma unroll
      for (int m = 0; m < 4; m++)
#pragma unroll
        for (int n = 0; n < 4; n++)
          acc[m][n] = __builtin_amdgcn_mfma_f32_16x16x32_f16(af[m], bf[n], acc[m][n], 0, 0, 0);
    }
    __syncthreads();
  }

  const int rowb = (lane >> 4) * 4;
#pragma unroll
  for (int m = 0; m < 4; m++) {
    int gm = m0 + wr * 64 + m * 16 + rowb;
#pragma unroll
    for (int n = 0; n < 4; n++) {
      int gn = n0 + wc * 64 + n * 16 + lr;
#pragma unroll
      for (int j = 0; j < 4; j++) {
        if (isFP)
          fp16[(size_t)(gm + j) * NH + gn] = (_Float16)(acc[m][n][j] + attn_b[gn]);
        else
          Gemb16[(size_t)(gm + j) * 3072 + gn] = (_Float16)acc[m][n][j];
      }
    }
  }
}

// ---------------- fc GEMM (256 thr, LDS-staged f32x4 epilogue) + folded tail ----------------
__global__ __launch_bounds__(256) void gemm_fc(
    const _Float16* __restrict__ A, const _Float16* __restrict__ Bt,
    float* __restrict__ out, const float* __restrict__ bias, int N,
    const float* __restrict__ hbuf, const float* __restrict__ cbuf) {
  constexpr int BK = 64;
  __shared__ __attribute__((aligned(16))) _Float16 sAB[256 * BK];
  _Float16* sA = sAB;
  _Float16* sB = sAB + 128 * BK;
  const int tid = threadIdx.x;
  if (blockIdx.x == 32) {  // folded k_tail: (h,c) -> out tail, grid-stride
    for (int i = blockIdx.y * 256 + tid; i < NB * NH; i += 79 * 256) {
      out[OUT_ELEMS + i] = hbuf[i];
      out[OUT_ELEMS + NB * NH + i] = cbuf[i];
    }
    return;
  }
  const int m0 = blockIdx.x * 128, n0 = blockIdx.y * 128;
  const int wid = tid >> 6, lane = tid & 63;
  const int wr = wid >> 1, wc = wid & 1;
  const int lr = lane & 15, lk = (lane >> 4) * 8;

  f32x4 acc[4][4] = {};

  for (int kt = 0; kt < 12; ++kt) {
    const int kbase = kt * BK;
#pragma unroll
    for (int i = 0; i < 4; i++) {
      int idx = tid + i * 256;
      int row = idx >> 3, seg = idx & 7;
      gld16(A + (size_t)(m0 + row) * NH + kbase + seg * 8, sA + idx * 8);
      int gr = n0 + row;
      if (gr >= N) gr = N - 1;
      gld16(Bt + (size_t)gr * NH + kbase + seg * 8, sB + idx * 8);
    }
    __syncthreads();
#pragma unroll
    for (int kk = 0; kk < 2; ++kk) {
      f16x8 af[4], bf[4];
#pragma unroll
      for (int m = 0; m < 4; m++)
        af[m] = *(const f16x8*)&sA[(wr * 64 + m * 16 + lr) * BK + kk * 32 + lk];
#pragma unroll
      for (int n = 0; n < 4; n++)
        bf[n] = *(const f16x8*)&sB[(wc * 64 + n * 16 + lr) * BK + kk * 32 + lk];
#pragma unroll
      for (int m = 0; m < 4; m++)
#pragma unroll
        for (int n = 0; n < 4; n++)
          acc[m][n] = __builtin_amdgcn_mfma_f32_16x16x32_f16(af[m], bf[n], acc[m][n], 0, 0, 0);
    }
    __syncthreads();
  }

  const int rowb = (lane >> 4) * 4;
  float* sC = (float*)sAB;  // 64x128 f32 = 32 KB
#pragma unroll
  for (int h = 0; h < 2; h++) {
    if (wr == h) {
#pragma unroll
      for (int m = 0; m < 4; m++)
#pragma unroll
        for (int n = 0; n < 4; n++)
#pragma unroll
          for (int j = 0; j < 4; j++)
            sC[(m * 16 + rowb + j) * 128 + wc * 64 + n * 16 + lr] = acc[m][n][j];
    }
    __syncthreads();
#pragma unroll
    for (int i = 0; i < 8; i++) {
      int lrow = (tid >> 5) + i * 8;
      int col = (tid & 31) * 4;
      int gn = n0 + col;
      if (gn < N) {
        int r = m0 + h * 64 + lrow;
        int tt = r >> 7, b = r & 127;
        f32x4 val = *(f32x4*)&sC[lrow * 128 + col];
        f32x4 bb = *(const f32x4*)&bias[gn];
        val += bb;
        *(f32x4*)&out[((size_t)(b * NT + tt)) * NV + gn] = val;
      }
    }
    __syncthreads();
  }
}

// ---------------- loop elementwise kernels (R9-proven) ----------------
__global__ __launch_bounds__(256) void k_scores(
    const _Float16* __restrict__ fp, const float* __restrict__ g1a,
    const float* __restrict__ v, float* __restrict__ sc) {
  int wid = threadIdx.x >> 6, lane = threadIdx.x & 63;
  int p = blockIdx.x * 4 + wid;  // 6272 = 1568 blocks * 4 waves
  int b = p / NR;
  const _Float16* fpr = fp + (size_t)p * NH;
  const float* hw0 = g1a + (size_t)b * NH;
  const float* hw1 = g1a + (size_t)NB * NH + (size_t)b * NH;
  const float* hw2 = g1a + (size_t)2 * NB * NH + (size_t)b * NH;
  float s = 0.f;
#pragma unroll
  for (int it = 0; it < 3; it++) {
    int h = it * 256 + lane * 4;
    f16x4 fv = *(const f16x4*)(fpr + h);
    f32x4 a0 = *(const f32x4*)(hw0 + h);
    f32x4 a1 = *(const f32x4*)(hw1 + h);
    f32x4 a2 = *(const f32x4*)(hw2 + h);
    f32x4 vv = *(const f32x4*)(v + h);
#pragma unroll
    for (int j = 0; j < 4; j++) s += fast_tanh((float)fv[j] + a0[j] + a1[j] + a2[j]) * vv[j];
  }
#pragma unroll
  for (int off = 32; off; off >>= 1) s += __shfl_down(s, off);
  if (lane == 0) sc[p] = s;
}

__global__ __launch_bounds__(256) void k_ctx(const float* __restrict__ sc,
                                             const _Float16* __restrict__ feat16,
                                             _Float16* __restrict__ ctx16) {
  __shared__ float al[64];
  int b = blockIdx.x, tid = threadIdx.x;
  if (tid < 64) {
    float s = (tid < NR) ? sc[b * NR + tid] : -1e30f;
    float m = s;
#pragma unroll
    for (int off = 32; off; off >>= 1) m = fmaxf(m, __shfl_xor(m, off));
    float e = (tid < NR) ? __expf(s - m) : 0.f;
    float su = e;
#pragma unroll
    for (int off = 32; off; off >>= 1) su += __shfl_xor(su, off);
    al[tid] = e / su;
  }
  __syncthreads();
  int f = blockIdx.y * 256 + tid;
  const _Float16* fb = feat16 + (size_t)b * NR * NH + f;
  float acc = 0.f;
#pragma unroll
  for (int r = 0; r < NR; r++) acc += al[r] * (float)fb[(size_t)r * NH];
  ctx16[(size_t)b * NH + f] = (_Float16)acc;
}

// LSTM: gates = Gemb[t] + sum of 4 partials in gbuf + biases
__global__ void k_lstm2(const _Float16* __restrict__ ge_t, const float* __restrict__ gbuf,
                        const float* __restrict__ b_ih, const float* __restrict__ b_hh,
                        float* __restrict__ h, float* __restrict__ c,
                        _Float16* __restrict__ h16, _Float16* __restrict__ Hall_t) {
  int b = blockIdx.x;
  int hh = blockIdx.y * 256 + threadIdx.x;
  const _Float16* ge = ge_t + (size_t)b * 3072;
  const float* p0 = gbuf + (size_t)b * 3072;
  const float* p1 = p0 + (size_t)NB * 3072;
  const float* p2 = p1 + (size_t)NB * 3072;
  const float* p3 = p2 + (size_t)NB * 3072;
  float gi = (float)ge[hh] + p0[hh] + p1[hh] + p2[hh] + p3[hh] + b_ih[hh] + b_hh[hh];
  float gf = (float)ge[768 + hh] + p0[768 + hh] + p1[768 + hh] + p2[768 + hh] + p3[768 + hh] +
             b_ih[768 + hh] + b_hh[768 + hh];
  float gg = (float)ge[1536 + hh] + p0[1536 + hh] + p1[1536 + hh] + p2[1536 + hh] +
             p3[1536 + hh] + b_ih[1536 + hh] + b_hh[1536 + hh];
  float go = (float)ge[2304 + hh] + p0[2304 + hh] + p1[2304 + hh] + p2[2304 + hh] +
             p3[2304 + hh] + b_ih[2304 + hh] + b_hh[2304 + hh];
  float i_ = sigm(gi), f_ = sigm(gf), g_ = fast_tanh(gg), o_ = sigm(go);
  float cn = f_ * c[b * NH + hh] + i_ * g_;
  float hn = o_ * fast_tanh(cn);
  c[b * NH + hh] = cn;
  h[b * NH + hh] = hn;
  h16[(size_t)b * NH + hh] = (_Float16)hn;
  Hall_t[(size_t)b * NH + hh] = (_Float16)hn;
}

// ---------------- phase-A prep: vectorized (4 elems/thread), block-range dispatch ----------------
// S0 feat16(4704) | S1 Wf16(576) | S2 Wh16(576) | S3 Whh16(2304) | S4 We(2304)
// | S5 Wc(2304) | S6 emb16(3072) | S7 init(384).  Total 16224 blocks.
__global__ void k_prep(const float* __restrict__ features, const float* __restrict__ attn_W,
                       const float* __restrict__ W_ih, const float* __restrict__ W_hh,
                       const int* __restrict__ captions, const float* __restrict__ emb_W,
                       _Float16* __restrict__ feat16, _Float16* __restrict__ Wf16,
                       _Float16* __restrict__ Wh16, _Float16* __restrict__ Whh16,
                       _Float16* __restrict__ We, _Float16* __restrict__ Wc,
                       _Float16* __restrict__ emb16, float* __restrict__ h,
                       float* __restrict__ c, _Float16* __restrict__ h16) {
  const int blk = blockIdx.x, tid = threadIdx.x;
  if (blk < 4704) {
    int q = (blk * 256 + tid) * 4;
    *(f16x4*)&feat16[q] = cvt4(*(const f32x4*)&features[q]);
  } else if (blk < 5280) {
    int q = ((blk - 4704) * 256 + tid) * 4;
    int j = q / NH, k = q - j * NH;
    *(f16x4*)&Wf16[q] = cvt4(*(const f32x4*)&attn_W[(size_t)j * 1536 + k]);
  } else if (blk < 5856) {
    int q = ((blk - 5280) * 256 + tid) * 4;
    int j = q / NH, k = q - j * NH;
    *(f16x4*)&Wh16[q] = cvt4(*(const f32x4*)&attn_W[(size_t)j * 1536 + 768 + k]);
  } else if (blk < 8160) {
    int q = ((blk - 5856) * 256 + tid) * 4;
    *(f16x4*)&Whh16[q] = cvt4(*(const f32x4*)&W_hh[q]);  // W_hh is contiguous (3072,768)
  } else if (blk < 10464) {
    int q = ((blk - 8160) * 256 + tid) * 4;
    int j = q / NH, k = q - j * NH;
    *(f16x4*)&We[q] = cvt4(*(const f32x4*)&W_ih[(size_t)j * 1536 + k]);
  } else if (blk < 12768) {
    int q = ((blk - 10464) * 256 + tid) * 4;
    int j = q / NH, k = q - j * NH;
    *(f16x4*)&Wc[q] = cvt4(*(const f32x4*)&W_ih[(size_t)j * 1536 + 768 + k]);
  } else if (blk < 15840) {
    int q = ((blk - 12768) * 256 + tid) * 4;
    int row = q / NH, k = q - row * NH;  // row = t*128+b
    int t = row >> 7, b = row & 127;
    int tok = captions[b * NT + t];
    *(f16x4*)&emb16[q] = cvt4(*(const f32x4*)&emb_W[(size_t)tok * NH + k]);
  } else {
    int q = blk - 15840;  // 384: b = q/3, f-chunk = q%3
    int b = q / 3;
    int f = (q - b * 3) * 256 + tid;
    float s = 0.f;
#pragma unroll 7
    for (int r = 0; r < NR; r++) s += features[((size_t)(b * NR + r)) * NH + f];
    float h0 = tanhf(s * (1.f / 49.f));
    h[b * NH + f] = h0;
    c[b * NH + f] = 0.f;
    h16[(size_t)b * NH + f] = (_Float16)h0;
  }
}

// vectorized f32 -> f16 (n must be divisible by 1024; 7,680,000 = 7500*1024)
__global__ void k_f32_to_f16v(const float* __restrict__ src, _Float16* __restrict__ dst) {
  int i = (blockIdx.x * 256 + threadIdx.x) * 4;
  *(f16x4*)&dst[i] = cvt4(*(const f32x4*)&src[i]);
}

// ---------------- host ----------------
extern "C" void kernel_launch(void* const* d_in, const int* in_sizes, int n_in,
                              void* d_out, int out_size, void* d_ws, size_t ws_size,
                              hipStream_t stream) {
  const float* features = (const float*)d_in[0];
  const int* captions = (const int*)d_in[1];
  const float* emb_W = (const float*)d_in[2];
  const float* attn_W = (const float*)d_in[3];
  const float* attn_b = (const float*)d_in[4];
  const float* attnv_W = (const float*)d_in[5];
  // d_in[6] attnv_b: constant shift, cancels in softmax
  const float* W_ih = (const float*)d_in[7];
  const float* W_hh = (const float*)d_in[8];
  const float* b_ih = (const float*)d_in[9];
  const float* b_hh = (const float*)d_in[10];
  const float* fc_W = (const float*)d_in[11];
  const float* fc_b = (const float*)d_in[12];
  float* out = (float*)d_out;

  char* p = (char*)d_ws;
  _Float16* Gemb16 = (_Float16*)p;  p += 25165824;  // (4096,3072); aliased by fcW16 after loop
  _Float16* fcW16 = Gemb16;                         // (10000,768), reuse after loop
  _Float16* emb16 = (_Float16*)p;   p += 6291456;   // (4096,768): row t*128+b
  _Float16* feat16 = (_Float16*)p;  p += 9633792;   // (6272,768)
  _Float16* fp16 = (_Float16*)p;    p += 9633792;   // feat_proj + attn_b (6272,768)
  _Float16* Wf16 = (_Float16*)p;    p += 1179648;   // (768,768)
  _Float16* Wh16 = (_Float16*)p;    p += 1179648;   // (768,768)
  _Float16* Whh16 = (_Float16*)p;   p += 4718592;   // (3072,768)
  _Float16* We16 = (_Float16*)p;    p += 4718592;   // (3072,768)
  _Float16* Wc16 = (_Float16*)p;    p += 4718592;   // (3072,768)
  _Float16* H_all = (_Float16*)p;   p += 6291456;   // (4096,768): row t*128+b
  float* g1a = (float*)p;           p += 1179648;   // 3 x (128,768) partials
  float* gbuf = (float*)p;          p += 6291456;   // 4 x (128,3072) partials
  float* scores = (float*)p;        p += 25088;     // (6272,)
  _Float16* ctx16 = (_Float16*)p;   p += 196608;    // (128,768)
  _Float16* h16 = (_Float16*)p;     p += 196608;    // (128,768)
  float* hbuf = (float*)p;          p += 393216;
  float* cbuf = (float*)p;          p += 393216;    // ~85 MB total

  // ---- phase A: 2 launches ----
  k_prep<<<dim3(16224), 256, 0, stream>>>(features, attn_W, W_ih, W_hh, captions, emb_W,
                                          feat16, Wf16, Wh16, Whh16, We16, Wc16, emb16,
                                          hbuf, cbuf, h16);
  // fp16 = feat@Wf.T + attn_b (294 blk) ; Gemb = emb@We.T (768 blk)
  gemm_phA<<<dim3(1062), 256, 0, stream>>>(feat16, Wf16, attn_b, fp16, emb16, We16, Gemb16);

  // ---- sequential scan: R9's proven 5 launches/step ----
  for (int t = 0; t < NT; t++) {
    if (t > 0)
      k_lstm2<<<dim3(128, 3), 256, 0, stream>>>(
          Gemb16 + (size_t)(t - 1) * NB * 3072, gbuf, b_ih, b_hh, hbuf, cbuf, h16,
          H_all + (size_t)(t - 1) * NB * NH);
    // g1a = h @ Wh.T  (128x768, K=768 split-K3 -> 4 ksteps, 72 blocks)
    gemm64<4, 256><<<dim3(2, 12, 3), 256, 0, stream>>>(h16, Wh16, g1a, NH);
    k_scores<<<dim3(1568), 256, 0, stream>>>(fp16, g1a, attnv_W, scores);
    k_ctx<<<dim3(128, 3), 256, 0, stream>>>(scores, feat16, ctx16);
    // gbuf[0,1] = ctx @ Wc.T halves; gbuf[2,3] = h @ Whh.T halves (384 blocks)
    gemm_g2m<<<dim3(2, 48, 4), 256, 0, stream>>>(ctx16, Wc16, h16, Whh16, gbuf);
  }
  k_lstm2<<<dim3(128, 3), 256, 0, stream>>>(
      Gemb16 + (size_t)(NT - 1) * NB * 3072, gbuf, b_ih, b_hh, hbuf, cbuf, h16,
      H_all + (size_t)(NT - 1) * NB * NH);

  // ---- fc (fcW16 aliases Gemb16, safe after last lstm in stream order) + tail fold ----
  k_f32_to_f16v<<<dim3(7500), 256, 0, stream>>>(fc_W, fcW16);
  gemm_fc<<<dim3(33, 79), 256, 0, stream>>>(H_all, fcW16, out, fc_b, NV, hbuf, cbuf);
}

// Round 12
// 1022.045 us; speedup vs baseline: 2.4757x; 1.0138x over previous
//
#include <hip/hip_runtime.h>

// SpatialAttentionLSTMDecoder on MI355X (gfx950). B=128,T=32,V=10000,F=H=768,R=49.
// R12 = R9 structure exactly (best: 1022.7us) + R11's vectorized prep/convert.
// Tail-fold REVERTED: changing fc grid (32,79)->(33,79) remapped blocks across
// XCDs and doubled fc FETCH (75->195MB, +13us). Loop frozen: 5 launches/step.
// No inter-block sync anywhere (R5: 118us/sync; R10: +47us/step — XCD-coherence).

typedef _Float16 f16x8 __attribute__((ext_vector_type(8)));
typedef _Float16 f16x4 __attribute__((ext_vector_type(4)));
typedef float f32x4 __attribute__((ext_vector_type(4)));

#define NB 128
#define NT 32
#define NV 10000
#define NH 768
#define NR 49
#define OUT_ELEMS 40960000  // B*T*V

__device__ __forceinline__ float fast_tanh(float x) {
  x = fminf(9.f, fmaxf(-9.f, x));
  float e = __expf(2.f * x);
  return (e - 1.f) / (e + 1.f);
}
__device__ __forceinline__ float sigm(float x) { return 1.f / (1.f + __expf(-x)); }

__device__ __forceinline__ void gld16(const void* g, void* l) {
  __builtin_amdgcn_global_load_lds((const __attribute__((address_space(1))) void*)g,
                                   (__attribute__((address_space(3))) void*)l, 16, 0, 0);
}

__device__ __forceinline__ f16x4 cvt4(f32x4 v) {
  f16x4 o;
#pragma unroll
  for (int j = 0; j < 4; j++) o[j] = (_Float16)v[j];
  return o;
}

// ---------------- 64x64 split-K GEMM (loop), EPI: f32 partial at z*128*N ----------------
template <int KSTEPS, int KSPLIT>
__global__ __launch_bounds__(256) void gemm64(
    const _Float16* __restrict__ A, const _Float16* __restrict__ Bt,
    float* __restrict__ C, int N) {
  constexpr int BK = 64;
  __shared__ __attribute__((aligned(16))) _Float16 sAB[128 * BK];
  _Float16* sA = sAB;
  _Float16* sB = sAB + 64 * BK;
  const int tid = threadIdx.x;
  const int m0 = blockIdx.x * 64, n0 = blockIdx.y * 64;
  const int z = blockIdx.z;
  A += (size_t)z * KSPLIT;
  Bt += (size_t)z * KSPLIT;
  C += (size_t)z * 128 * N;

  const int wid = tid >> 6, lane = tid & 63;
  const int wr = wid >> 1, wc = wid & 1;
  const int lr = lane & 15, lk = (lane >> 4) * 8;

  f32x4 acc[2][2] = {};

  for (int kt = 0; kt < KSTEPS; ++kt) {
    const int kbase = kt * BK;
#pragma unroll
    for (int i = 0; i < 2; i++) {
      int idx = tid + i * 256;
      int row = idx >> 3, seg = idx & 7;
      gld16(A + (size_t)(m0 + row) * NH + kbase + seg * 8, sA + idx * 8);
      gld16(Bt + (size_t)(n0 + row) * NH + kbase + seg * 8, sB + idx * 8);
    }
    __syncthreads();
#pragma unroll
    for (int kk = 0; kk < 2; ++kk) {
      f16x8 af[2], bf[2];
#pragma unroll
      for (int m = 0; m < 2; m++)
        af[m] = *(const f16x8*)&sA[(wr * 32 + m * 16 + lr) * BK + kk * 32 + lk];
#pragma unroll
      for (int n = 0; n < 2; n++)
        bf[n] = *(const f16x8*)&sB[(wc * 32 + n * 16 + lr) * BK + kk * 32 + lk];
#pragma unroll
      for (int m = 0; m < 2; m++)
#pragma unroll
        for (int n = 0; n < 2; n++)
          acc[m][n] = __builtin_amdgcn_mfma_f32_16x16x32_f16(af[m], bf[n], acc[m][n], 0, 0, 0);
    }
    __syncthreads();
  }

  const int rowb = (lane >> 4) * 4;
#pragma unroll
  for (int m = 0; m < 2; m++) {
    int gm = m0 + wr * 32 + m * 16 + rowb;
#pragma unroll
    for (int n = 0; n < 2; n++) {
      int gn = n0 + wc * 32 + n * 16 + lr;
#pragma unroll
      for (int j = 0; j < 4; j++) C[(size_t)(gm + j) * N + gn] = acc[m][n][j];
    }
  }
}

// ---------------- g2m: merged ctx@Wc (z=0,1) + h@Whh (z=2,3), splitK2 each ----------------
__global__ __launch_bounds__(256) void gemm_g2m(
    const _Float16* __restrict__ ctx16, const _Float16* __restrict__ Wc,
    const _Float16* __restrict__ h16, const _Float16* __restrict__ Whh,
    float* __restrict__ C) {
  constexpr int BK = 64;
  __shared__ __attribute__((aligned(16))) _Float16 sAB[128 * BK];
  _Float16* sA = sAB;
  _Float16* sB = sAB + 64 * BK;
  const int tid = threadIdx.x;
  const int m0 = blockIdx.x * 64, n0 = blockIdx.y * 64;
  const int z = blockIdx.z;
  const _Float16* A = (z >> 1) ? h16 : ctx16;
  const _Float16* Bt = (z >> 1) ? Whh : Wc;
  A += (size_t)(z & 1) * 384;
  Bt += (size_t)(z & 1) * 384;
  C += (size_t)z * 128 * 3072;

  const int wid = tid >> 6, lane = tid & 63;
  const int wr = wid >> 1, wc = wid & 1;
  const int lr = lane & 15, lk = (lane >> 4) * 8;

  f32x4 acc[2][2] = {};

  for (int kt = 0; kt < 6; ++kt) {
    const int kbase = kt * BK;
#pragma unroll
    for (int i = 0; i < 2; i++) {
      int idx = tid + i * 256;
      int row = idx >> 3, seg = idx & 7;
      gld16(A + (size_t)(m0 + row) * NH + kbase + seg * 8, sA + idx * 8);
      gld16(Bt + (size_t)(n0 + row) * NH + kbase + seg * 8, sB + idx * 8);
    }
    __syncthreads();
#pragma unroll
    for (int kk = 0; kk < 2; ++kk) {
      f16x8 af[2], bf[2];
#pragma unroll
      for (int m = 0; m < 2; m++)
        af[m] = *(const f16x8*)&sA[(wr * 32 + m * 16 + lr) * BK + kk * 32 + lk];
#pragma unroll
      for (int n = 0; n < 2; n++)
        bf[n] = *(const f16x8*)&sB[(wc * 32 + n * 16 + lr) * BK + kk * 32 + lk];
#pragma unroll
      for (int m = 0; m < 2; m++)
#pragma unroll
        for (int n = 0; n < 2; n++)
          acc[m][n] = __builtin_amdgcn_mfma_f32_16x16x32_f16(af[m], bf[n], acc[m][n], 0, 0, 0);
    }
    __syncthreads();
  }

  const int rowb = (lane >> 4) * 4;
#pragma unroll
  for (int m = 0; m < 2; m++) {
    int gm = m0 + wr * 32 + m * 16 + rowb;
#pragma unroll
    for (int n = 0; n < 2; n++) {
      int gn = n0 + wc * 32 + n * 16 + lr;
#pragma unroll
      for (int j = 0; j < 4; j++) C[(size_t)(gm + j) * 3072 + gn] = acc[m][n][j];
    }
  }
}

// ---------------- phase-A merged 128x128 GEMM: fp16 proj (294 blk) + Gemb (768 blk) ----------------
__global__ __launch_bounds__(256) void gemm_phA(
    const _Float16* __restrict__ feat16, const _Float16* __restrict__ Wf16,
    const float* __restrict__ attn_b, _Float16* __restrict__ fp16,
    const _Float16* __restrict__ emb16, const _Float16* __restrict__ We16,
    _Float16* __restrict__ Gemb16) {
  constexpr int BK = 64;
  __shared__ __attribute__((aligned(16))) _Float16 sAB[256 * BK];
  _Float16* sA = sAB;
  _Float16* sB = sAB + 128 * BK;
  const int blk = blockIdx.x, tid = threadIdx.x;
  const bool isFP = blk < 294;
  const int bx = isFP ? (blk % 49) : ((blk - 294) % 32);
  const int by = isFP ? (blk / 49) : ((blk - 294) / 32);
  const _Float16* A = isFP ? feat16 : emb16;
  const _Float16* Bt = isFP ? Wf16 : We16;
  const int m0 = bx * 128, n0 = by * 128;

  const int wid = tid >> 6, lane = tid & 63;
  const int wr = wid >> 1, wc = wid & 1;
  const int lr = lane & 15, lk = (lane >> 4) * 8;

  f32x4 acc[4][4] = {};

  for (int kt = 0; kt < 12; ++kt) {
    const int kbase = kt * BK;
#pragma unroll
    for (int i = 0; i < 4; i++) {
      int idx = tid + i * 256;
      int row = idx >> 3, seg = idx & 7;
      gld16(A + (size_t)(m0 + row) * NH + kbase + seg * 8, sA + idx * 8);
      gld16(Bt + (size_t)(n0 + row) * NH + kbase + seg * 8, sB + idx * 8);
    }
    __syncthreads();
#pragma unroll
    for (int kk = 0; kk < 2; ++kk) {
      f16x8 af[4], bf[4];
#pragma unroll
      for (int m = 0; m < 4; m++)
        af[m] = *(const f16x8*)&sA[(wr * 64 + m * 16 + lr) * BK + kk * 32 + lk];
#pragma unroll
      for (int n = 0; n < 4; n++)
        bf[n] = *(const f16x8*)&sB[(wc * 64 + n * 16 + lr) * BK + kk * 32 + lk];
#pragma unroll
      for (int m = 0; m < 4; m++)
#pragma unroll
        for (int n = 0; n < 4; n++)
          acc[m][n] = __builtin_amdgcn_mfma_f32_16x16x32_f16(af[m], bf[n], acc[m][n], 0, 0, 0);
    }
    __syncthreads();
  }

  const int rowb = (lane >> 4) * 4;
#pragma unroll
  for (int m = 0; m < 4; m++) {
    int gm = m0 + wr * 64 + m * 16 + rowb;
#pragma unroll
    for (int n = 0; n < 4; n++) {
      int gn = n0 + wc * 64 + n * 16 + lr;
#pragma unroll
      for (int j = 0; j < 4; j++) {
        if (isFP)
          fp16[(size_t)(gm + j) * NH + gn] = (_Float16)(acc[m][n][j] + attn_b[gn]);
        else
          Gemb16[(size_t)(gm + j) * 3072 + gn] = (_Float16)acc[m][n][j];
      }
    }
  }
}

// ---------------- fc GEMM: R9-proven, grid (32,79), LDS-staged f32x4 epilogue ----------------
__global__ __launch_bounds__(256) void gemm_fc(
    const _Float16* __restrict__ A, const _Float16* __restrict__ Bt,
    float* __restrict__ out, const float* __restrict__ bias, int N) {
  constexpr int BK = 64;
  __shared__ __attribute__((aligned(16))) _Float16 sAB[256 * BK];
  _Float16* sA = sAB;
  _Float16* sB = sAB + 128 * BK;
  const int tid = threadIdx.x;
  const int m0 = blockIdx.x * 128, n0 = blockIdx.y * 128;
  const int wid = tid >> 6, lane = tid & 63;
  const int wr = wid >> 1, wc = wid & 1;
  const int lr = lane & 15, lk = (lane >> 4) * 8;

  f32x4 acc[4][4] = {};

  for (int kt = 0; kt < 12; ++kt) {
    const int kbase = kt * BK;
#pragma unroll
    for (int i = 0; i < 4; i++) {
      int idx = tid + i * 256;
      int row = idx >> 3, seg = idx & 7;
      gld16(A + (size_t)(m0 + row) * NH + kbase + seg * 8, sA + idx * 8);
      int gr = n0 + row;
      if (gr >= N) gr = N - 1;
      gld16(Bt + (size_t)gr * NH + kbase + seg * 8, sB + idx * 8);
    }
    __syncthreads();
#pragma unroll
    for (int kk = 0; kk < 2; ++kk) {
      f16x8 af[4], bf[4];
#pragma unroll
      for (int m = 0; m < 4; m++)
        af[m] = *(const f16x8*)&sA[(wr * 64 + m * 16 + lr) * BK + kk * 32 + lk];
#pragma unroll
      for (int n = 0; n < 4; n++)
        bf[n] = *(const f16x8*)&sB[(wc * 64 + n * 16 + lr) * BK + kk * 32 + lk];
#pragma unroll
      for (int m = 0; m < 4; m++)
#pragma unroll
        for (int n = 0; n < 4; n++)
          acc[m][n] = __builtin_amdgcn_mfma_f32_16x16x32_f16(af[m], bf[n], acc[m][n], 0, 0, 0);
    }
    __syncthreads();
  }

  const int rowb = (lane >> 4) * 4;
  float* sC = (float*)sAB;  // 64x128 f32 = 32 KB
#pragma unroll
  for (int h = 0; h < 2; h++) {
    if (wr == h) {
#pragma unroll
      for (int m = 0; m < 4; m++)
#pragma unroll
        for (int n = 0; n < 4; n++)
#pragma unroll
          for (int j = 0; j < 4; j++)
            sC[(m * 16 + rowb + j) * 128 + wc * 64 + n * 16 + lr] = acc[m][n][j];
    }
    __syncthreads();
#pragma unroll
    for (int i = 0; i < 8; i++) {
      int lrow = (tid >> 5) + i * 8;
      int col = (tid & 31) * 4;
      int gn = n0 + col;
      if (gn < N) {
        int r = m0 + h * 64 + lrow;
        int tt = r >> 7, b = r & 127;
        f32x4 val = *(f32x4*)&sC[lrow * 128 + col];
        f32x4 bb = *(const f32x4*)&bias[gn];
        val += bb;
        *(f32x4*)&out[((size_t)(b * NT + tt)) * NV + gn] = val;
      }
    }
    __syncthreads();
  }
}

// ---------------- loop elementwise kernels (R9-proven) ----------------
__global__ __launch_bounds__(256) void k_scores(
    const _Float16* __restrict__ fp, const float* __restrict__ g1a,
    const float* __restrict__ v, float* __restrict__ sc) {
  int wid = threadIdx.x >> 6, lane = threadIdx.x & 63;
  int p = blockIdx.x * 4 + wid;  // 6272 = 1568 blocks * 4 waves
  int b = p / NR;
  const _Float16* fpr = fp + (size_t)p * NH;
  const float* hw0 = g1a + (size_t)b * NH;
  const float* hw1 = g1a + (size_t)NB * NH + (size_t)b * NH;
  const float* hw2 = g1a + (size_t)2 * NB * NH + (size_t)b * NH;
  float s = 0.f;
#pragma unroll
  for (int it = 0; it < 3; it++) {
    int h = it * 256 + lane * 4;
    f16x4 fv = *(const f16x4*)(fpr + h);
    f32x4 a0 = *(const f32x4*)(hw0 + h);
    f32x4 a1 = *(const f32x4*)(hw1 + h);
    f32x4 a2 = *(const f32x4*)(hw2 + h);
    f32x4 vv = *(const f32x4*)(v + h);
#pragma unroll
    for (int j = 0; j < 4; j++) s += fast_tanh((float)fv[j] + a0[j] + a1[j] + a2[j]) * vv[j];
  }
#pragma unroll
  for (int off = 32; off; off >>= 1) s += __shfl_down(s, off);
  if (lane == 0) sc[p] = s;
}

__global__ __launch_bounds__(256) void k_ctx(const float* __restrict__ sc,
                                             const _Float16* __restrict__ feat16,
                                             _Float16* __restrict__ ctx16) {
  __shared__ float al[64];
  int b = blockIdx.x, tid = threadIdx.x;
  if (tid < 64) {
    float s = (tid < NR) ? sc[b * NR + tid] : -1e30f;
    float m = s;
#pragma unroll
    for (int off = 32; off; off >>= 1) m = fmaxf(m, __shfl_xor(m, off));
    float e = (tid < NR) ? __expf(s - m) : 0.f;
    float su = e;
#pragma unroll
    for (int off = 32; off; off >>= 1) su += __shfl_xor(su, off);
    al[tid] = e / su;
  }
  __syncthreads();
  int f = blockIdx.y * 256 + tid;
  const _Float16* fb = feat16 + (size_t)b * NR * NH + f;
  float acc = 0.f;
#pragma unroll
  for (int r = 0; r < NR; r++) acc += al[r] * (float)fb[(size_t)r * NH];
  ctx16[(size_t)b * NH + f] = (_Float16)acc;
}

// LSTM: gates = Gemb[t] + sum of 4 partials in gbuf + biases
__global__ void k_lstm2(const _Float16* __restrict__ ge_t, const float* __restrict__ gbuf,
                        const float* __restrict__ b_ih, const float* __restrict__ b_hh,
                        float* __restrict__ h, float* __restrict__ c,
                        _Float16* __restrict__ h16, _Float16* __restrict__ Hall_t) {
  int b = blockIdx.x;
  int hh = blockIdx.y * 256 + threadIdx.x;
  const _Float16* ge = ge_t + (size_t)b * 3072;
  const float* p0 = gbuf + (size_t)b * 3072;
  const float* p1 = p0 + (size_t)NB * 3072;
  const float* p2 = p1 + (size_t)NB * 3072;
  const float* p3 = p2 + (size_t)NB * 3072;
  float gi = (float)ge[hh] + p0[hh] + p1[hh] + p2[hh] + p3[hh] + b_ih[hh] + b_hh[hh];
  float gf = (float)ge[768 + hh] + p0[768 + hh] + p1[768 + hh] + p2[768 + hh] + p3[768 + hh] +
             b_ih[768 + hh] + b_hh[768 + hh];
  float gg = (float)ge[1536 + hh] + p0[1536 + hh] + p1[1536 + hh] + p2[1536 + hh] +
             p3[1536 + hh] + b_ih[1536 + hh] + b_hh[1536 + hh];
  float go = (float)ge[2304 + hh] + p0[2304 + hh] + p1[2304 + hh] + p2[2304 + hh] +
             p3[2304 + hh] + b_ih[2304 + hh] + b_hh[2304 + hh];
  float i_ = sigm(gi), f_ = sigm(gf), g_ = fast_tanh(gg), o_ = sigm(go);
  float cn = f_ * c[b * NH + hh] + i_ * g_;
  float hn = o_ * fast_tanh(cn);
  c[b * NH + hh] = cn;
  h[b * NH + hh] = hn;
  h16[(size_t)b * NH + hh] = (_Float16)hn;
  Hall_t[(size_t)b * NH + hh] = (_Float16)hn;
}

// ---------------- phase-A prep: vectorized (4 elems/thread), block-range dispatch ----------------
__global__ void k_prep(const float* __restrict__ features, const float* __restrict__ attn_W,
                       const float* __restrict__ W_ih, const float* __restrict__ W_hh,
                       const int* __restrict__ captions, const float* __restrict__ emb_W,
                       _Float16* __restrict__ feat16, _Float16* __restrict__ Wf16,
                       _Float16* __restrict__ Wh16, _Float16* __restrict__ Whh16,
                       _Float16* __restrict__ We, _Float16* __restrict__ Wc,
                       _Float16* __restrict__ emb16, float* __restrict__ h,
                       float* __restrict__ c, _Float16* __restrict__ h16) {
  const int blk = blockIdx.x, tid = threadIdx.x;
  if (blk < 4704) {
    int q = (blk * 256 + tid) * 4;
    *(f16x4*)&feat16[q] = cvt4(*(const f32x4*)&features[q]);
  } else if (blk < 5280) {
    int q = ((blk - 4704) * 256 + tid) * 4;
    int j = q / NH, k = q - j * NH;
    *(f16x4*)&Wf16[q] = cvt4(*(const f32x4*)&attn_W[(size_t)j * 1536 + k]);
  } else if (blk < 5856) {
    int q = ((blk - 5280) * 256 + tid) * 4;
    int j = q / NH, k = q - j * NH;
    *(f16x4*)&Wh16[q] = cvt4(*(const f32x4*)&attn_W[(size_t)j * 1536 + 768 + k]);
  } else if (blk < 8160) {
    int q = ((blk - 5856) * 256 + tid) * 4;
    *(f16x4*)&Whh16[q] = cvt4(*(const f32x4*)&W_hh[q]);  // W_hh contiguous (3072,768)
  } else if (blk < 10464) {
    int q = ((blk - 8160) * 256 + tid) * 4;
    int j = q / NH, k = q - j * NH;
    *(f16x4*)&We[q] = cvt4(*(const f32x4*)&W_ih[(size_t)j * 1536 + k]);
  } else if (blk < 12768) {
    int q = ((blk - 10464) * 256 + tid) * 4;
    int j = q / NH, k = q - j * NH;
    *(f16x4*)&Wc[q] = cvt4(*(const f32x4*)&W_ih[(size_t)j * 1536 + 768 + k]);
  } else if (blk < 15840) {
    int q = ((blk - 12768) * 256 + tid) * 4;
    int row = q / NH, k = q - row * NH;  // row = t*128+b
    int t = row >> 7, b = row & 127;
    int tok = captions[b * NT + t];
    *(f16x4*)&emb16[q] = cvt4(*(const f32x4*)&emb_W[(size_t)tok * NH + k]);
  } else {
    int q = blk - 15840;  // 384: b = q/3, f-chunk = q%3
    int b = q / 3;
    int f = (q - b * 3) * 256 + tid;
    float s = 0.f;
#pragma unroll 7
    for (int r = 0; r < NR; r++) s += features[((size_t)(b * NR + r)) * NH + f];
    float h0 = tanhf(s * (1.f / 49.f));
    h[b * NH + f] = h0;
    c[b * NH + f] = 0.f;
    h16[(size_t)b * NH + f] = (_Float16)h0;
  }
}

// vectorized f32 -> f16 (7,680,000 = 7500*1024)
__global__ void k_f32_to_f16v(const float* __restrict__ src, _Float16* __restrict__ dst) {
  int i = (blockIdx.x * 256 + threadIdx.x) * 4;
  *(f16x4*)&dst[i] = cvt4(*(const f32x4*)&src[i]);
}

__global__ void k_tail(const float* __restrict__ h, const float* __restrict__ c,
                       float* __restrict__ out) {
  int i = blockIdx.x * 256 + threadIdx.x;  // 98304
  out[OUT_ELEMS + i] = h[i];
  out[OUT_ELEMS + NB * NH + i] = c[i];
}

// ---------------- host ----------------
extern "C" void kernel_launch(void* const* d_in, const int* in_sizes, int n_in,
                              void* d_out, int out_size, void* d_ws, size_t ws_size,
                              hipStream_t stream) {
  const float* features = (const float*)d_in[0];
  const int* captions = (const int*)d_in[1];
  const float* emb_W = (const float*)d_in[2];
  const float* attn_W = (const float*)d_in[3];
  const float* attn_b = (const float*)d_in[4];
  const float* attnv_W = (const float*)d_in[5];
  // d_in[6] attnv_b: constant shift, cancels in softmax
  const float* W_ih = (const float*)d_in[7];
  const float* W_hh = (const float*)d_in[8];
  const float* b_ih = (const float*)d_in[9];
  const float* b_hh = (const float*)d_in[10];
  const float* fc_W = (const float*)d_in[11];
  const float* fc_b = (const float*)d_in[12];
  float* out = (float*)d_out;

  char* p = (char*)d_ws;
  _Float16* Gemb16 = (_Float16*)p;  p += 25165824;  // (4096,3072); aliased by fcW16 after loop
  _Float16* fcW16 = Gemb16;                         // (10000,768), reuse after loop
  _Float16* emb16 = (_Float16*)p;   p += 6291456;   // (4096,768): row t*128+b
  _Float16* feat16 = (_Float16*)p;  p += 9633792;   // (6272,768)
  _Float16* fp16 = (_Float16*)p;    p += 9633792;   // feat_proj + attn_b (6272,768)
  _Float16* Wf16 = (_Float16*)p;    p += 1179648;   // (768,768)
  _Float16* Wh16 = (_Float16*)p;    p += 1179648;   // (768,768)
  _Float16* Whh16 = (_Float16*)p;   p += 4718592;   // (3072,768)
  _Float16* We16 = (_Float16*)p;    p += 4718592;   // (3072,768)
  _Float16* Wc16 = (_Float16*)p;    p += 4718592;   // (3072,768)
  _Float16* H_all = (_Float16*)p;   p += 6291456;   // (4096,768): row t*128+b
  float* g1a = (float*)p;           p += 1179648;   // 3 x (128,768) partials
  float* gbuf = (float*)p;          p += 6291456;   // 4 x (128,3072) partials
  float* scores = (float*)p;        p += 25088;     // (6272,)
  _Float16* ctx16 = (_Float16*)p;   p += 196608;    // (128,768)
  _Float16* h16 = (_Float16*)p;     p += 196608;    // (128,768)
  float* hbuf = (float*)p;          p += 393216;
  float* cbuf = (float*)p;          p += 393216;    // ~85 MB total

  // ---- phase A: 2 launches ----
  k_prep<<<dim3(16224), 256, 0, stream>>>(features, attn_W, W_ih, W_hh, captions, emb_W,
                                          feat16, Wf16, Wh16, Whh16, We16, Wc16, emb16,
                                          hbuf, cbuf, h16);
  // fp16 = feat@Wf.T + attn_b (294 blk) ; Gemb = emb@We.T (768 blk)
  gemm_phA<<<dim3(1062), 256, 0, stream>>>(feat16, Wf16, attn_b, fp16, emb16, We16, Gemb16);

  // ---- sequential scan: R9's proven 5 launches/step ----
  for (int t = 0; t < NT; t++) {
    if (t > 0)
      k_lstm2<<<dim3(128, 3), 256, 0, stream>>>(
          Gemb16 + (size_t)(t - 1) * NB * 3072, gbuf, b_ih, b_hh, hbuf, cbuf, h16,
          H_all + (size_t)(t - 1) * NB * NH);
    // g1a = h @ Wh.T  (128x768, K=768 split-K3 -> 4 ksteps, 72 blocks)
    gemm64<4, 256><<<dim3(2, 12, 3), 256, 0, stream>>>(h16, Wh16, g1a, NH);
    k_scores<<<dim3(1568), 256, 0, stream>>>(fp16, g1a, attnv_W, scores);
    k_ctx<<<dim3(128, 3), 256, 0, stream>>>(scores, feat16, ctx16);
    // gbuf[0,1] = ctx @ Wc.T halves; gbuf[2,3] = h @ Whh.T halves (384 blocks)
    gemm_g2m<<<dim3(2, 48, 4), 256, 0, stream>>>(ctx16, Wc16, h16, Whh16, gbuf);
  }
  k_lstm2<<<dim3(128, 3), 256, 0, stream>>>(
      Gemb16 + (size_t)(NT - 1) * NB * 3072, gbuf, b_ih, b_hh, hbuf, cbuf, h16,
      H_all + (size_t)(NT - 1) * NB * NH);

  // ---- fc (fcW16 aliases Gemb16, safe after last lstm in stream order) ----
  k_f32_to_f16v<<<dim3(7500), 256, 0, stream>>>(fc_W, fcW16);
  gemm_fc<<<dim3(32, 79), 256, 0, stream>>>(H_all, fcW16, out, fc_b, NV);
  k_tail<<<dim3(384), 256, 0, stream>>>(hbuf, cbuf, out);
}

// Round 13
// 1017.845 us; speedup vs baseline: 2.4859x; 1.0041x over previous
//
#include <hip/hip_runtime.h>

// SpatialAttentionLSTMDecoder on MI355X (gfx950). B=128,T=32,V=10000,F=H=768,R=49.
// R13 = R12 (1022.0us) + T1 bijective XCD swizzle inside gemm_fc (grid stays
// (32,79); 2528=8*316 exactly) + k_tail folded into k_f32_to_f16v (geometry-
// insensitive, unlike R11's failed fc-grid fold). All else bit-identical.
// Loop frozen: 5 launches/step; no inter-block sync (R5/R10 lessons).

typedef _Float16 f16x8 __attribute__((ext_vector_type(8)));
typedef _Float16 f16x4 __attribute__((ext_vector_type(4)));
typedef float f32x4 __attribute__((ext_vector_type(4)));

#define NB 128
#define NT 32
#define NV 10000
#define NH 768
#define NR 49
#define OUT_ELEMS 40960000  // B*T*V

__device__ __forceinline__ float fast_tanh(float x) {
  x = fminf(9.f, fmaxf(-9.f, x));
  float e = __expf(2.f * x);
  return (e - 1.f) / (e + 1.f);
}
__device__ __forceinline__ float sigm(float x) { return 1.f / (1.f + __expf(-x)); }

__device__ __forceinline__ void gld16(const void* g, void* l) {
  __builtin_amdgcn_global_load_lds((const __attribute__((address_space(1))) void*)g,
                                   (__attribute__((address_space(3))) void*)l, 16, 0, 0);
}

__device__ __forceinline__ f16x4 cvt4(f32x4 v) {
  f16x4 o;
#pragma unroll
  for (int j = 0; j < 4; j++) o[j] = (_Float16)v[j];
  return o;
}

// ---------------- 64x64 split-K GEMM (loop), EPI: f32 partial at z*128*N ----------------
template <int KSTEPS, int KSPLIT>
__global__ __launch_bounds__(256) void gemm64(
    const _Float16* __restrict__ A, const _Float16* __restrict__ Bt,
    float* __restrict__ C, int N) {
  constexpr int BK = 64;
  __shared__ __attribute__((aligned(16))) _Float16 sAB[128 * BK];
  _Float16* sA = sAB;
  _Float16* sB = sAB + 64 * BK;
  const int tid = threadIdx.x;
  const int m0 = blockIdx.x * 64, n0 = blockIdx.y * 64;
  const int z = blockIdx.z;
  A += (size_t)z * KSPLIT;
  Bt += (size_t)z * KSPLIT;
  C += (size_t)z * 128 * N;

  const int wid = tid >> 6, lane = tid & 63;
  const int wr = wid >> 1, wc = wid & 1;
  const int lr = lane & 15, lk = (lane >> 4) * 8;

  f32x4 acc[2][2] = {};

  for (int kt = 0; kt < KSTEPS; ++kt) {
    const int kbase = kt * BK;
#pragma unroll
    for (int i = 0; i < 2; i++) {
      int idx = tid + i * 256;
      int row = idx >> 3, seg = idx & 7;
      gld16(A + (size_t)(m0 + row) * NH + kbase + seg * 8, sA + idx * 8);
      gld16(Bt + (size_t)(n0 + row) * NH + kbase + seg * 8, sB + idx * 8);
    }
    __syncthreads();
#pragma unroll
    for (int kk = 0; kk < 2; ++kk) {
      f16x8 af[2], bf[2];
#pragma unroll
      for (int m = 0; m < 2; m++)
        af[m] = *(const f16x8*)&sA[(wr * 32 + m * 16 + lr) * BK + kk * 32 + lk];
#pragma unroll
      for (int n = 0; n < 2; n++)
        bf[n] = *(const f16x8*)&sB[(wc * 32 + n * 16 + lr) * BK + kk * 32 + lk];
#pragma unroll
      for (int m = 0; m < 2; m++)
#pragma unroll
        for (int n = 0; n < 2; n++)
          acc[m][n] = __builtin_amdgcn_mfma_f32_16x16x32_f16(af[m], bf[n], acc[m][n], 0, 0, 0);
    }
    __syncthreads();
  }

  const int rowb = (lane >> 4) * 4;
#pragma unroll
  for (int m = 0; m < 2; m++) {
    int gm = m0 + wr * 32 + m * 16 + rowb;
#pragma unroll
    for (int n = 0; n < 2; n++) {
      int gn = n0 + wc * 32 + n * 16 + lr;
#pragma unroll
      for (int j = 0; j < 4; j++) C[(size_t)(gm + j) * N + gn] = acc[m][n][j];
    }
  }
}

// ---------------- g2m: merged ctx@Wc (z=0,1) + h@Whh (z=2,3), splitK2 each ----------------
__global__ __launch_bounds__(256) void gemm_g2m(
    const _Float16* __restrict__ ctx16, const _Float16* __restrict__ Wc,
    const _Float16* __restrict__ h16, const _Float16* __restrict__ Whh,
    float* __restrict__ C) {
  constexpr int BK = 64;
  __shared__ __attribute__((aligned(16))) _Float16 sAB[128 * BK];
  _Float16* sA = sAB;
  _Float16* sB = sAB + 64 * BK;
  const int tid = threadIdx.x;
  const int m0 = blockIdx.x * 64, n0 = blockIdx.y * 64;
  const int z = blockIdx.z;
  const _Float16* A = (z >> 1) ? h16 : ctx16;
  const _Float16* Bt = (z >> 1) ? Whh : Wc;
  A += (size_t)(z & 1) * 384;
  Bt += (size_t)(z & 1) * 384;
  C += (size_t)z * 128 * 3072;

  const int wid = tid >> 6, lane = tid & 63;
  const int wr = wid >> 1, wc = wid & 1;
  const int lr = lane & 15, lk = (lane >> 4) * 8;

  f32x4 acc[2][2] = {};

  for (int kt = 0; kt < 6; ++kt) {
    const int kbase = kt * BK;
#pragma unroll
    for (int i = 0; i < 2; i++) {
      int idx = tid + i * 256;
      int row = idx >> 3, seg = idx & 7;
      gld16(A + (size_t)(m0 + row) * NH + kbase + seg * 8, sA + idx * 8);
      gld16(Bt + (size_t)(n0 + row) * NH + kbase + seg * 8, sB + idx * 8);
    }
    __syncthreads();
#pragma unroll
    for (int kk = 0; kk < 2; ++kk) {
      f16x8 af[2], bf[2];
#pragma unroll
      for (int m = 0; m < 2; m++)
        af[m] = *(const f16x8*)&sA[(wr * 32 + m * 16 + lr) * BK + kk * 32 + lk];
#pragma unroll
      for (int n = 0; n < 2; n++)
        bf[n] = *(const f16x8*)&sB[(wc * 32 + n * 16 + lr) * BK + kk * 32 + lk];
#pragma unroll
      for (int m = 0; m < 2; m++)
#pragma unroll
        for (int n = 0; n < 2; n++)
          acc[m][n] = __builtin_amdgcn_mfma_f32_16x16x32_f16(af[m], bf[n], acc[m][n], 0, 0, 0);
    }
    __syncthreads();
  }

  const int rowb = (lane >> 4) * 4;
#pragma unroll
  for (int m = 0; m < 2; m++) {
    int gm = m0 + wr * 32 + m * 16 + rowb;
#pragma unroll
    for (int n = 0; n < 2; n++) {
      int gn = n0 + wc * 32 + n * 16 + lr;
#pragma unroll
      for (int j = 0; j < 4; j++) C[(size_t)(gm + j) * 3072 + gn] = acc[m][n][j];
    }
  }
}

// ---------------- phase-A merged 128x128 GEMM: fp16 proj (294 blk) + Gemb (768 blk) ----------------
__global__ __launch_bounds__(256) void gemm_phA(
    const _Float16* __restrict__ feat16, const _Float16* __restrict__ Wf16,
    const float* __restrict__ attn_b, _Float16* __restrict__ fp16,
    const _Float16* __restrict__ emb16, const _Float16* __restrict__ We16,
    _Float16* __restrict__ Gemb16) {
  constexpr int BK = 64;
  __shared__ __attribute__((aligned(16))) _Float16 sAB[256 * BK];
  _Float16* sA = sAB;
  _Float16* sB = sAB + 128 * BK;
  const int blk = blockIdx.x, tid = threadIdx.x;
  const bool isFP = blk < 294;
  const int bx = isFP ? (blk % 49) : ((blk - 294) % 32);
  const int by = isFP ? (blk / 49) : ((blk - 294) / 32);
  const _Float16* A = isFP ? feat16 : emb16;
  const _Float16* Bt = isFP ? Wf16 : We16;
  const int m0 = bx * 128, n0 = by * 128;

  const int wid = tid >> 6, lane = tid & 63;
  const int wr = wid >> 1, wc = wid & 1;
  const int lr = lane & 15, lk = (lane >> 4) * 8;

  f32x4 acc[4][4] = {};

  for (int kt = 0; kt < 12; ++kt) {
    const int kbase = kt * BK;
#pragma unroll
    for (int i = 0; i < 4; i++) {
      int idx = tid + i * 256;
      int row = idx >> 3, seg = idx & 7;
      gld16(A + (size_t)(m0 + row) * NH + kbase + seg * 8, sA + idx * 8);
      gld16(Bt + (size_t)(n0 + row) * NH + kbase + seg * 8, sB + idx * 8);
    }
    __syncthreads();
#pragma unroll
    for (int kk = 0; kk < 2; ++kk) {
      f16x8 af[4], bf[4];
#pragma unroll
      for (int m = 0; m < 4; m++)
        af[m] = *(const f16x8*)&sA[(wr * 64 + m * 16 + lr) * BK + kk * 32 + lk];
#pragma unroll
      for (int n = 0; n < 4; n++)
        bf[n] = *(const f16x8*)&sB[(wc * 64 + n * 16 + lr) * BK + kk * 32 + lk];
#pragma unroll
      for (int m = 0; m < 4; m++)
#pragma unroll
        for (int n = 0; n < 4; n++)
          acc[m][n] = __builtin_amdgcn_mfma_f32_16x16x32_f16(af[m], bf[n], acc[m][n], 0, 0, 0);
    }
    __syncthreads();
  }

  const int rowb = (lane >> 4) * 4;
#pragma unroll
  for (int m = 0; m < 4; m++) {
    int gm = m0 + wr * 64 + m * 16 + rowb;
#pragma unroll
    for (int n = 0; n < 4; n++) {
      int gn = n0 + wc * 64 + n * 16 + lr;
#pragma unroll
      for (int j = 0; j < 4; j++) {
        if (isFP)
          fp16[(size_t)(gm + j) * NH + gn] = (_Float16)(acc[m][n][j] + attn_b[gn]);
        else
          Gemb16[(size_t)(gm + j) * 3072 + gn] = (_Float16)acc[m][n][j];
      }
    }
  }
}

// ---------------- fc GEMM: grid (32,79), XCD-swizzled work id, LDS-staged epilogue ----------------
__global__ __launch_bounds__(256) void gemm_fc(
    const _Float16* __restrict__ A, const _Float16* __restrict__ Bt,
    float* __restrict__ out, const float* __restrict__ bias, int N) {
  constexpr int BK = 64;
  __shared__ __attribute__((aligned(16))) _Float16 sAB[256 * BK];
  _Float16* sA = sAB;
  _Float16* sB = sAB + 128 * BK;
  const int tid = threadIdx.x;
  // T1 bijective XCD swizzle: nwg = 2528 = 8 * 316. Dispatch d -> XCD d%8;
  // give each XCD a contiguous chunk of the (B-panel-major) work list.
  const int d = blockIdx.x + blockIdx.y * 32;
  const int work = (d & 7) * 316 + (d >> 3);
  const int m0 = (work & 31) * 128, n0 = (work >> 5) * 128;
  const int wid = tid >> 6, lane = tid & 63;
  const int wr = wid >> 1, wc = wid & 1;
  const int lr = lane & 15, lk = (lane >> 4) * 8;

  f32x4 acc[4][4] = {};

  for (int kt = 0; kt < 12; ++kt) {
    const int kbase = kt * BK;
#pragma unroll
    for (int i = 0; i < 4; i++) {
      int idx = tid + i * 256;
      int row = idx >> 3, seg = idx & 7;
      gld16(A + (size_t)(m0 + row) * NH + kbase + seg * 8, sA + idx * 8);
      int gr = n0 + row;
      if (gr >= N) gr = N - 1;
      gld16(Bt + (size_t)gr * NH + kbase + seg * 8, sB + idx * 8);
    }
    __syncthreads();
#pragma unroll
    for (int kk = 0; kk < 2; ++kk) {
      f16x8 af[4], bf[4];
#pragma unroll
      for (int m = 0; m < 4; m++)
        af[m] = *(const f16x8*)&sA[(wr * 64 + m * 16 + lr) * BK + kk * 32 + lk];
#pragma unroll
      for (int n = 0; n < 4; n++)
        bf[n] = *(const f16x8*)&sB[(wc * 64 + n * 16 + lr) * BK + kk * 32 + lk];
#pragma unroll
      for (int m = 0; m < 4; m++)
#pragma unroll
        for (int n = 0; n < 4; n++)
          acc[m][n] = __builtin_amdgcn_mfma_f32_16x16x32_f16(af[m], bf[n], acc[m][n], 0, 0, 0);
    }
    __syncthreads();
  }

  const int rowb = (lane >> 4) * 4;
  float* sC = (float*)sAB;  // 64x128 f32 = 32 KB
#pragma unroll
  for (int h = 0; h < 2; h++) {
    if (wr == h) {
#pragma unroll
      for (int m = 0; m < 4; m++)
#pragma unroll
        for (int n = 0; n < 4; n++)
#pragma unroll
          for (int j = 0; j < 4; j++)
            sC[(m * 16 + rowb + j) * 128 + wc * 64 + n * 16 + lr] = acc[m][n][j];
    }
    __syncthreads();
#pragma unroll
    for (int i = 0; i < 8; i++) {
      int lrow = (tid >> 5) + i * 8;
      int col = (tid & 31) * 4;
      int gn = n0 + col;
      if (gn < N) {
        int r = m0 + h * 64 + lrow;
        int tt = r >> 7, b = r & 127;
        f32x4 val = *(f32x4*)&sC[lrow * 128 + col];
        f32x4 bb = *(const f32x4*)&bias[gn];
        val += bb;
        *(f32x4*)&out[((size_t)(b * NT + tt)) * NV + gn] = val;
      }
    }
    __syncthreads();
  }
}

// ---------------- loop elementwise kernels (R9-proven) ----------------
__global__ __launch_bounds__(256) void k_scores(
    const _Float16* __restrict__ fp, const float* __restrict__ g1a,
    const float* __restrict__ v, float* __restrict__ sc) {
  int wid = threadIdx.x >> 6, lane = threadIdx.x & 63;
  int p = blockIdx.x * 4 + wid;  // 6272 = 1568 blocks * 4 waves
  int b = p / NR;
  const _Float16* fpr = fp + (size_t)p * NH;
  const float* hw0 = g1a + (size_t)b * NH;
  const float* hw1 = g1a + (size_t)NB * NH + (size_t)b * NH;
  const float* hw2 = g1a + (size_t)2 * NB * NH + (size_t)b * NH;
  float s = 0.f;
#pragma unroll
  for (int it = 0; it < 3; it++) {
    int h = it * 256 + lane * 4;
    f16x4 fv = *(const f16x4*)(fpr + h);
    f32x4 a0 = *(const f32x4*)(hw0 + h);
    f32x4 a1 = *(const f32x4*)(hw1 + h);
    f32x4 a2 = *(const f32x4*)(hw2 + h);
    f32x4 vv = *(const f32x4*)(v + h);
#pragma unroll
    for (int j = 0; j < 4; j++) s += fast_tanh((float)fv[j] + a0[j] + a1[j] + a2[j]) * vv[j];
  }
#pragma unroll
  for (int off = 32; off; off >>= 1) s += __shfl_down(s, off);
  if (lane == 0) sc[p] = s;
}

__global__ __launch_bounds__(256) void k_ctx(const float* __restrict__ sc,
                                             const _Float16* __restrict__ feat16,
                                             _Float16* __restrict__ ctx16) {
  __shared__ float al[64];
  int b = blockIdx.x, tid = threadIdx.x;
  if (tid < 64) {
    float s = (tid < NR) ? sc[b * NR + tid] : -1e30f;
    float m = s;
#pragma unroll
    for (int off = 32; off; off >>= 1) m = fmaxf(m, __shfl_xor(m, off));
    float e = (tid < NR) ? __expf(s - m) : 0.f;
    float su = e;
#pragma unroll
    for (int off = 32; off; off >>= 1) su += __shfl_xor(su, off);
    al[tid] = e / su;
  }
  __syncthreads();
  int f = blockIdx.y * 256 + tid;
  const _Float16* fb = feat16 + (size_t)b * NR * NH + f;
  float acc = 0.f;
#pragma unroll
  for (int r = 0; r < NR; r++) acc += al[r] * (float)fb[(size_t)r * NH];
  ctx16[(size_t)b * NH + f] = (_Float16)acc;
}

// LSTM: gates = Gemb[t] + sum of 4 partials in gbuf + biases
__global__ void k_lstm2(const _Float16* __restrict__ ge_t, const float* __restrict__ gbuf,
                        const float* __restrict__ b_ih, const float* __restrict__ b_hh,
                        float* __restrict__ h, float* __restrict__ c,
                        _Float16* __restrict__ h16, _Float16* __restrict__ Hall_t) {
  int b = blockIdx.x;
  int hh = blockIdx.y * 256 + threadIdx.x;
  const _Float16* ge = ge_t + (size_t)b * 3072;
  const float* p0 = gbuf + (size_t)b * 3072;
  const float* p1 = p0 + (size_t)NB * 3072;
  const float* p2 = p1 + (size_t)NB * 3072;
  const float* p3 = p2 + (size_t)NB * 3072;
  float gi = (float)ge[hh] + p0[hh] + p1[hh] + p2[hh] + p3[hh] + b_ih[hh] + b_hh[hh];
  float gf = (float)ge[768 + hh] + p0[768 + hh] + p1[768 + hh] + p2[768 + hh] + p3[768 + hh] +
             b_ih[768 + hh] + b_hh[768 + hh];
  float gg = (float)ge[1536 + hh] + p0[1536 + hh] + p1[1536 + hh] + p2[1536 + hh] +
             p3[1536 + hh] + b_ih[1536 + hh] + b_hh[1536 + hh];
  float go = (float)ge[2304 + hh] + p0[2304 + hh] + p1[2304 + hh] + p2[2304 + hh] +
             p3[2304 + hh] + b_ih[2304 + hh] + b_hh[2304 + hh];
  float i_ = sigm(gi), f_ = sigm(gf), g_ = fast_tanh(gg), o_ = sigm(go);
  float cn = f_ * c[b * NH + hh] + i_ * g_;
  float hn = o_ * fast_tanh(cn);
  c[b * NH + hh] = cn;
  h[b * NH + hh] = hn;
  h16[(size_t)b * NH + hh] = (_Float16)hn;
  Hall_t[(size_t)b * NH + hh] = (_Float16)hn;
}

// ---------------- phase-A prep: vectorized (4 elems/thread), block-range dispatch ----------------
__global__ void k_prep(const float* __restrict__ features, const float* __restrict__ attn_W,
                       const float* __restrict__ W_ih, const float* __restrict__ W_hh,
                       const int* __restrict__ captions, const float* __restrict__ emb_W,
                       _Float16* __restrict__ feat16, _Float16* __restrict__ Wf16,
                       _Float16* __restrict__ Wh16, _Float16* __restrict__ Whh16,
                       _Float16* __restrict__ We, _Float16* __restrict__ Wc,
                       _Float16* __restrict__ emb16, float* __restrict__ h,
                       float* __restrict__ c, _Float16* __restrict__ h16) {
  const int blk = blockIdx.x, tid = threadIdx.x;
  if (blk < 4704) {
    int q = (blk * 256 + tid) * 4;
    *(f16x4*)&feat16[q] = cvt4(*(const f32x4*)&features[q]);
  } else if (blk < 5280) {
    int q = ((blk - 4704) * 256 + tid) * 4;
    int j = q / NH, k = q - j * NH;
    *(f16x4*)&Wf16[q] = cvt4(*(const f32x4*)&attn_W[(size_t)j * 1536 + k]);
  } else if (blk < 5856) {
    int q = ((blk - 5280) * 256 + tid) * 4;
    int j = q / NH, k = q - j * NH;
    *(f16x4*)&Wh16[q] = cvt4(*(const f32x4*)&attn_W[(size_t)j * 1536 + 768 + k]);
  } else if (blk < 8160) {
    int q = ((blk - 5856) * 256 + tid) * 4;
    *(f16x4*)&Whh16[q] = cvt4(*(const f32x4*)&W_hh[q]);  // W_hh contiguous (3072,768)
  } else if (blk < 10464) {
    int q = ((blk - 8160) * 256 + tid) * 4;
    int j = q / NH, k = q - j * NH;
    *(f16x4*)&We[q] = cvt4(*(const f32x4*)&W_ih[(size_t)j * 1536 + k]);
  } else if (blk < 12768) {
    int q = ((blk - 10464) * 256 + tid) * 4;
    int j = q / NH, k = q - j * NH;
    *(f16x4*)&Wc[q] = cvt4(*(const f32x4*)&W_ih[(size_t)j * 1536 + 768 + k]);
  } else if (blk < 15840) {
    int q = ((blk - 12768) * 256 + tid) * 4;
    int row = q / NH, k = q - row * NH;  // row = t*128+b
    int t = row >> 7, b = row & 127;
    int tok = captions[b * NT + t];
    *(f16x4*)&emb16[q] = cvt4(*(const f32x4*)&emb_W[(size_t)tok * NH + k]);
  } else {
    int q = blk - 15840;  // 384: b = q/3, f-chunk = q%3
    int b = q / 3;
    int f = (q - b * 3) * 256 + tid;
    float s = 0.f;
#pragma unroll 7
    for (int r = 0; r < NR; r++) s += features[((size_t)(b * NR + r)) * NH + f];
    float h0 = tanhf(s * (1.f / 49.f));
    h[b * NH + f] = h0;
    c[b * NH + f] = 0.f;
    h16[(size_t)b * NH + f] = (_Float16)h0;
  }
}

// vectorized f32 -> f16 (7500 blocks) + folded (h,c) tail copy (blocks 7500..7883)
__global__ void k_f32_to_f16v(const float* __restrict__ src, _Float16* __restrict__ dst,
                              const float* __restrict__ h, const float* __restrict__ c,
                              float* __restrict__ out) {
  const int blk = blockIdx.x;
  if (blk >= 7500) {
    int i = (blk - 7500) * 256 + threadIdx.x;  // 98304 = 384*256
    out[OUT_ELEMS + i] = h[i];
    out[OUT_ELEMS + NB * NH + i] = c[i];
    return;
  }
  int i = (blk * 256 + threadIdx.x) * 4;
  *(f16x4*)&dst[i] = cvt4(*(const f32x4*)&src[i]);
}

// ---------------- host ----------------
extern "C" void kernel_launch(void* const* d_in, const int* in_sizes, int n_in,
                              void* d_out, int out_size, void* d_ws, size_t ws_size,
                              hipStream_t stream) {
  const float* features = (const float*)d_in[0];
  const int* captions = (const int*)d_in[1];
  const float* emb_W = (const float*)d_in[2];
  const float* attn_W = (const float*)d_in[3];
  const float* attn_b = (const float*)d_in[4];
  const float* attnv_W = (const float*)d_in[5];
  // d_in[6] attnv_b: constant shift, cancels in softmax
  const float* W_ih = (const float*)d_in[7];
  const float* W_hh = (const float*)d_in[8];
  const float* b_ih = (const float*)d_in[9];
  const float* b_hh = (const float*)d_in[10];
  const float* fc_W = (const float*)d_in[11];
  const float* fc_b = (const float*)d_in[12];
  float* out = (float*)d_out;

  char* p = (char*)d_ws;
  _Float16* Gemb16 = (_Float16*)p;  p += 25165824;  // (4096,3072); aliased by fcW16 after loop
  _Float16* fcW16 = Gemb16;                         // (10000,768), reuse after loop
  _Float16* emb16 = (_Float16*)p;   p += 6291456;   // (4096,768): row t*128+b
  _Float16* feat16 = (_Float16*)p;  p += 9633792;   // (6272,768)
  _Float16* fp16 = (_Float16*)p;    p += 9633792;   // feat_proj + attn_b (6272,768)
  _Float16* Wf16 = (_Float16*)p;    p += 1179648;   // (768,768)
  _Float16* Wh16 = (_Float16*)p;    p += 1179648;   // (768,768)
  _Float16* Whh16 = (_Float16*)p;   p += 4718592;   // (3072,768)
  _Float16* We16 = (_Float16*)p;    p += 4718592;   // (3072,768)
  _Float16* Wc16 = (_Float16*)p;    p += 4718592;   // (3072,768)
  _Float16* H_all = (_Float16*)p;   p += 6291456;   // (4096,768): row t*128+b
  float* g1a = (float*)p;           p += 1179648;   // 3 x (128,768) partials
  float* gbuf = (float*)p;          p += 6291456;   // 4 x (128,3072) partials
  float* scores = (float*)p;        p += 25088;     // (6272,)
  _Float16* ctx16 = (_Float16*)p;   p += 196608;    // (128,768)
  _Float16* h16 = (_Float16*)p;     p += 196608;    // (128,768)
  float* hbuf = (float*)p;          p += 393216;
  float* cbuf = (float*)p;          p += 393216;    // ~85 MB total

  // ---- phase A: 2 launches ----
  k_prep<<<dim3(16224), 256, 0, stream>>>(features, attn_W, W_ih, W_hh, captions, emb_W,
                                          feat16, Wf16, Wh16, Whh16, We16, Wc16, emb16,
                                          hbuf, cbuf, h16);
  // fp16 = feat@Wf.T + attn_b (294 blk) ; Gemb = emb@We.T (768 blk)
  gemm_phA<<<dim3(1062), 256, 0, stream>>>(feat16, Wf16, attn_b, fp16, emb16, We16, Gemb16);

  // ---- sequential scan: R9's proven 5 launches/step ----
  for (int t = 0; t < NT; t++) {
    if (t > 0)
      k_lstm2<<<dim3(128, 3), 256, 0, stream>>>(
          Gemb16 + (size_t)(t - 1) * NB * 3072, gbuf, b_ih, b_hh, hbuf, cbuf, h16,
          H_all + (size_t)(t - 1) * NB * NH);
    // g1a = h @ Wh.T  (128x768, K=768 split-K3 -> 4 ksteps, 72 blocks)
    gemm64<4, 256><<<dim3(2, 12, 3), 256, 0, stream>>>(h16, Wh16, g1a, NH);
    k_scores<<<dim3(1568), 256, 0, stream>>>(fp16, g1a, attnv_W, scores);
    k_ctx<<<dim3(128, 3), 256, 0, stream>>>(scores, feat16, ctx16);
    // gbuf[0,1] = ctx @ Wc.T halves; gbuf[2,3] = h @ Whh.T halves (384 blocks)
    gemm_g2m<<<dim3(2, 48, 4), 256, 0, stream>>>(ctx16, Wc16, h16, Whh16, gbuf);
  }
  k_lstm2<<<dim3(128, 3), 256, 0, stream>>>(
      Gemb16 + (size_t)(NT - 1) * NB * 3072, gbuf, b_ih, b_hh, hbuf, cbuf, h16,
      H_all + (size_t)(NT - 1) * NB * NH);

  // ---- fc convert (+folded tail) then fc GEMM (fcW16 aliases Gemb16) ----
  k_f32_to_f16v<<<dim3(7884), 256, 0, stream>>>(fc_W, fcW16, hbuf, cbuf, out);
  gemm_fc<<<dim3(32, 79), 256, 0, stream>>>(H_all, fcW16, out, fc_b, NV);
}